// Round 1
// baseline (584.282 us; speedup 1.0000x reference)
//
#include <hip/hip_runtime.h>
#include <hip/hip_bf16.h>

// EdgeConv fused GNN. R5: software-pipelined gathers in msg_kernel.
// - All weights in LDS (staged once, XOR-swizzled for conflict-free b128 reads)
// - No barriers in hot loop: each wave owns independent 16-edge tiles
// - NEW: next tile's h[src]/h[dst]/ea rows prefetched into registers (1 tile deep),
//   edge indices prefetched 2 tiles deep; first tile's gathers issued BEFORE
//   weight staging so they overlap the staging + syncthreads.
// - Inter-layer transpose via 4KB per-wave LDS act buffer (swizzled)
// - LayerNorm fully in registers via __shfl_xor
// - Aggregation by CSR gather (no fp atomics), quad-per-edge float4 loads.

typedef __attribute__((ext_vector_type(8))) short s16x8;   // MFMA A/B frag (8 bf16)
typedef __attribute__((ext_vector_type(4))) float f32x4;   // MFMA C/D frag

__device__ __forceinline__ unsigned short f2bf(float x) {
  union { float f; unsigned u; } v; v.f = x;
  unsigned r = v.u + 0x7fffu + ((v.u >> 16) & 1u);   // RNE
  return (unsigned short)(r >> 16);
}

// pack 8 fp32 (two float4) -> bf16 frag
__device__ __forceinline__ s16x8 cvt8(float4 a, float4 b) {
  union { s16x8 v; __hip_bfloat162 h2[4]; } u;
  float2 t;
  t.x = a.x; t.y = a.y; u.h2[0] = __float22bfloat162_rn(t);
  t.x = a.z; t.y = a.w; u.h2[1] = __float22bfloat162_rn(t);
  t.x = b.x; t.y = b.y; u.h2[2] = __float22bfloat162_rn(t);
  t.x = b.z; t.y = b.w; u.h2[3] = __float22bfloat162_rn(t);
  return u.v;
}

// ---------------- weight transpose+convert into final (swizzled) layout ----------------
// ushort offsets in wts:
//  mW1t @0     : 128 rows x stride 168 (k<160, unswizzled; pad never read)
//  mW2t @21504 : 128 x 128, XOR-swizzled
//  mW3t @37888 :  64 x 128, XOR-swizzled
//  uW1t @46080 : 128 x 128, uW2t @62464, uW3t @78848 (64x128); total 87040 ushorts
__global__ __launch_bounds__(256) void wconv(
    const float* __restrict__ mW1, const float* __restrict__ mW2, const float* __restrict__ mW3,
    const float* __restrict__ uW1, const float* __restrict__ uW2, const float* __restrict__ uW3,
    unsigned short* __restrict__ wts) {
  int t = blockIdx.x * 256 + threadIdx.x;
  const float* src; int K, N, off, base;
  if      (t < 20480) { src = mW1; K = 160; N = 128; off = 0;     base = 0;     }
  else if (t < 36864) { src = mW2; K = 128; N = 128; off = 20480; base = 21504; }
  else if (t < 45056) { src = mW3; K = 128; N = 64;  off = 36864; base = 37888; }
  else if (t < 61440) { src = uW1; K = 128; N = 128; off = 45056; base = 46080; }
  else if (t < 77824) { src = uW2; K = 128; N = 128; off = 61440; base = 62464; }
  else if (t < 86016) { src = uW3; K = 128; N = 64;  off = 77824; base = 78848; }
  else return;
  int local = t - off;
  int n = local / K, k = local - n * K;
  int idx;
  if (K == 160) idx = n * 168 + k;                                        // mW1t: padded, plain
  else          idx = base + n * 128 + ((((k >> 3) ^ (n & 7)) << 3) | (k & 7));
  wts[idx] = f2bf(src[k * N + n]);
}

// ---------------- CSR build ----------------
__global__ __launch_bounds__(256) void hist_kernel(const int* __restrict__ dstI,
                                                   int* __restrict__ deg, int E) {
  int t = blockIdx.x * 256 + threadIdx.x;
  if (t < E) atomicAdd(&deg[dstI[t]], 1);
}

__global__ __launch_bounds__(1024) void scan_kernel(const int* __restrict__ deg,
                                                    int* __restrict__ rowptr,
                                                    int* __restrict__ cursor, int Nn) {
  __shared__ int part[1024], offs[1024];
  int t = threadIdx.x;
  int C = (Nn + 1023) / 1024;
  int lo = t * C, hi = lo + C < Nn ? lo + C : Nn;
  int sum = 0;
  for (int i = lo; i < hi; i++) sum += deg[i];
  part[t] = sum;
  __syncthreads();
  if (t == 0) {
    int run = 0;
    for (int i = 0; i < 1024; i++) { offs[i] = run; run += part[i]; }
  }
  __syncthreads();
  int run = offs[t];
  for (int i = lo; i < hi; i++) { rowptr[i] = run; cursor[i] = run; run += deg[i]; }
  if (t == 1023) rowptr[Nn] = offs[1023] + part[1023];
}

__global__ __launch_bounds__(256) void scatter_kernel(const int* __restrict__ dstI,
                                                      int* __restrict__ cursor,
                                                      int* __restrict__ csr, int E) {
  int t = blockIdx.x * 256 + threadIdx.x;
  if (t < E) {
    int pos = atomicAdd(&cursor[dstI[t]], 1);
    csr[pos] = t;
  }
}

// ---------------- message MLP: persistent blocks, 16 waves, 16 edges/tile/wave ----------------
__global__ __launch_bounds__(1024, 4) void msg_kernel(
    const float* __restrict__ h, const int* __restrict__ ei, const float* __restrict__ ea,
    const unsigned short* __restrict__ wts,
    const float* __restrict__ mb1, const float* __restrict__ mb2, const float* __restrict__ mb3,
    const float* __restrict__ mg, const float* __restrict__ mbt,
    float* __restrict__ msg_out, int E) {
  __shared__ __align__(16) unsigned short lds[78848];   // 157,696 B
  const int tid = threadIdx.x;
  const int w = tid >> 6, lane = tid & 63, quad = lane >> 4, l15 = lane & 15;
  const int sw = l15 & 7;
  const int* srcI = ei;
  const int* dstI = ei + E;
  const int ntiles = (E + 15) >> 4;
  const int stride = gridDim.x * 16;
  int tile = blockIdx.x * 16 + w;

  // ---- prologue: issue first tile's gathers BEFORE staging (latency rides under it)
  float4 P[10];
  int sN = 0, dN = 0;
  if (tile < ntiles) {
    int e = (tile << 4) + l15; int ec = e < E ? e : E - 1;
    int s = srcI[ec], d = dstI[ec];
    const float* rs = h + (size_t)s * 64 + quad * 8;
    const float* rd = h + (size_t)d * 64 + quad * 8;
    const float* re = ea + (size_t)ec * 32 + quad * 8;
    P[0] = *(const float4*)rs;        P[1] = *(const float4*)(rs + 4);
    P[2] = *(const float4*)(rs + 32); P[3] = *(const float4*)(rs + 36);
    P[4] = *(const float4*)rd;        P[5] = *(const float4*)(rd + 4);
    P[6] = *(const float4*)(rd + 32); P[7] = *(const float4*)(rd + 36);
    P[8] = *(const float4*)re;        P[9] = *(const float4*)(re + 4);
    int tn = tile + stride;
    if (tn < ntiles) {
      int e2 = (tn << 4) + l15; int ec2 = e2 < E ? e2 : E - 1;
      sN = srcI[ec2]; dN = dstI[ec2];
    }
  }

  // stage all msg weights (46080 ushorts) once
  for (int i = tid; i < 5760; i += 1024)
    *(s16x8*)&lds[i * 8] = *(const s16x8*)&wts[i * 8];
  __syncthreads();

  unsigned short* act = &lds[46080 + w * 2048];         // per-wave 4KB, swizzled, stride 128
  const unsigned short* W1 = &lds[0];
  const unsigned short* W2 = &lds[21504];
  const unsigned short* W3 = &lds[37888];

  // hoisted per-lane constants
  float b1c[8], b2c[8], b3c[4], gc[4], btc[4];
  #pragma unroll
  for (int nt = 0; nt < 8; nt++) { b1c[nt] = mb1[nt * 16 + l15]; b2c[nt] = mb2[nt * 16 + l15]; }
  #pragma unroll
  for (int nt = 0; nt < 4; nt++) { b3c[nt] = mb3[nt * 16 + l15]; gc[nt] = mg[nt * 16 + l15]; btc[nt] = mbt[nt * 16 + l15]; }

  for (; tile < ntiles; tile += stride) {
    const int e0 = tile << 4;

    // consume prefetched rows (waits on the loads issued a full tile ago)
    s16x8 fa[5];
    fa[0] = cvt8(P[0], P[1]);
    fa[1] = cvt8(P[2], P[3]);
    fa[2] = cvt8(P[4], P[5]);
    fa[3] = cvt8(P[6], P[7]);
    fa[4] = cvt8(P[8], P[9]);

    // ---- L1: 160 -> 128, B from LDS (stride 168, naturally conflict-free)
    f32x4 acc[8];
    #pragma unroll
    for (int nt = 0; nt < 8; nt++) acc[nt] = (f32x4){0.f, 0.f, 0.f, 0.f};
    #pragma unroll
    for (int kb = 0; kb < 5; kb++) {
      #pragma unroll
      for (int nt = 0; nt < 8; nt++) {
        s16x8 b = *(const s16x8*)&W1[(nt * 16 + l15) * 168 + kb * 32 + quad * 8];
        acc[nt] = __builtin_amdgcn_mfma_f32_16x16x32_bf16(fa[kb], b, acc[nt], 0, 0, 0);
      }
    }
    // act1 = relu(acc + b1), bf16, swizzled (col = nt*16+l15 -> block 2nt+(l15>>3))
    #pragma unroll
    for (int nt = 0; nt < 8; nt++) {
      int cb = 2 * nt + (l15 >> 3);
      #pragma unroll
      for (int r = 0; r < 4; r++) {
        int row = quad * 4 + r;
        float v = acc[nt][r] + b1c[nt];
        v = v > 0.f ? v : 0.f;
        act[row * 128 + ((cb ^ (row & 7)) << 3) + sw] = f2bf(v);
      }
    }

    // ---- prefetch next tile's rows (fa is dead now; P regs free to refill).
    // Gather latency hides under L2+L3+LN (~2000 cy of compute below).
    {
      int tn = tile + stride;
      if (tn < ntiles) {
        const float* rs = h + (size_t)sN * 64 + quad * 8;
        const float* rd = h + (size_t)dN * 64 + quad * 8;
        int en = (tn << 4) + l15; int ecn = en < E ? en : E - 1;
        const float* re = ea + (size_t)ecn * 32 + quad * 8;
        P[0] = *(const float4*)rs;        P[1] = *(const float4*)(rs + 4);
        P[2] = *(const float4*)(rs + 32); P[3] = *(const float4*)(rs + 36);
        P[4] = *(const float4*)rd;        P[5] = *(const float4*)(rd + 4);
        P[6] = *(const float4*)(rd + 32); P[7] = *(const float4*)(rd + 36);
        P[8] = *(const float4*)re;        P[9] = *(const float4*)(re + 4);
        int tn2 = tn + stride;
        if (tn2 < ntiles) {
          int e2 = (tn2 << 4) + l15; int ec2 = e2 < E ? e2 : E - 1;
          sN = srcI[ec2]; dN = dstI[ec2];
        }
      }
    }

    // ---- L2: 128 -> 128 (A from act, B from W2; both swizzled stride 128)
    f32x4 acc2[8];
    #pragma unroll
    for (int nt = 0; nt < 8; nt++) acc2[nt] = (f32x4){0.f, 0.f, 0.f, 0.f};
    #pragma unroll
    for (int kb = 0; kb < 4; kb++) {
      int blk8 = (((kb << 2) + quad) ^ sw) << 3;
      s16x8 a = *(const s16x8*)&act[l15 * 128 + blk8];
      #pragma unroll
      for (int nt = 0; nt < 8; nt++) {
        s16x8 b = *(const s16x8*)&W2[(nt * 16 + l15) * 128 + blk8];
        acc2[nt] = __builtin_amdgcn_mfma_f32_16x16x32_bf16(a, b, acc2[nt], 0, 0, 0);
      }
    }
    // act2 overwrites act (all reads consumed)
    #pragma unroll
    for (int nt = 0; nt < 8; nt++) {
      int cb = 2 * nt + (l15 >> 3);
      #pragma unroll
      for (int r = 0; r < 4; r++) {
        int row = quad * 4 + r;
        float v = acc2[nt][r] + b2c[nt];
        v = v > 0.f ? v : 0.f;
        act[row * 128 + ((cb ^ (row & 7)) << 3) + sw] = f2bf(v);
      }
    }

    // ---- L3: 128 -> 64
    f32x4 acc3[4];
    #pragma unroll
    for (int nt = 0; nt < 4; nt++) acc3[nt] = (f32x4){0.f, 0.f, 0.f, 0.f};
    #pragma unroll
    for (int kb = 0; kb < 4; kb++) {
      int blk8 = (((kb << 2) + quad) ^ sw) << 3;
      s16x8 a = *(const s16x8*)&act[l15 * 128 + blk8];
      #pragma unroll
      for (int nt = 0; nt < 4; nt++) {
        s16x8 b = *(const s16x8*)&W3[(nt * 16 + l15) * 128 + blk8];
        acc3[nt] = __builtin_amdgcn_mfma_f32_16x16x32_bf16(a, b, acc3[nt], 0, 0, 0);
      }
    }

    // ---- LayerNorm in registers (rows = quad*4+r, cols nt*16+l15) + store
    #pragma unroll
    for (int r = 0; r < 4; r++) {
      float v0 = acc3[0][r] + b3c[0];
      float v1 = acc3[1][r] + b3c[1];
      float v2 = acc3[2][r] + b3c[2];
      float v3 = acc3[3][r] + b3c[3];
      float p = v0 + v1 + v2 + v3;
      float q = v0 * v0 + v1 * v1 + v2 * v2 + v3 * v3;
      #pragma unroll
      for (int m = 1; m <= 8; m <<= 1) {
        p += __shfl_xor(p, m);
        q += __shfl_xor(q, m);
      }
      float mu = p * (1.f / 64.f);
      float var = q * (1.f / 64.f) - mu * mu;
      float rstd = rsqrtf(var + 1e-5f);
      int row = e0 + quad * 4 + r;
      if (row < E) {
        float* mp = msg_out + (size_t)row * 64 + l15;
        mp[0]  = (v0 - mu) * rstd * gc[0] + btc[0];
        mp[16] = (v1 - mu) * rstd * gc[1] + btc[1];
        mp[32] = (v2 - mu) * rstd * gc[2] + btc[2];
        mp[48] = (v3 - mu) * rstd * gc[3] + btc[3];
      }
    }
  }
}

// ---------------- aggregation by gather: one node per wave, quad-per-edge float4 ----------------
__global__ __launch_bounds__(256) void agg_kernel(
    const float* __restrict__ msg, const int* __restrict__ rowptr,
    const int* __restrict__ csr, float* __restrict__ agg, int Nn) {
  int node = (blockIdx.x * 256 + threadIdx.x) >> 6;
  int lane = threadIdx.x & 63;
  int eo = lane >> 4, l = lane & 15;
  if (node >= Nn) return;
  int s = rowptr[node], e = rowptr[node + 1];
  float4 a = {0.f, 0.f, 0.f, 0.f};
  for (int j = s + eo; j < e; j += 4) {
    const float4 m = *(const float4*)&msg[(size_t)csr[j] * 64 + l * 4];
    a.x += m.x; a.y += m.y; a.z += m.z; a.w += m.w;
  }
  // reduce the 4 quads
  a.x += __shfl_xor(a.x, 16); a.y += __shfl_xor(a.y, 16);
  a.z += __shfl_xor(a.z, 16); a.w += __shfl_xor(a.w, 16);
  a.x += __shfl_xor(a.x, 32); a.y += __shfl_xor(a.y, 32);
  a.z += __shfl_xor(a.z, 32); a.w += __shfl_xor(a.w, 32);
  if (eo == 0) *(float4*)&agg[(size_t)node * 64 + l * 4] = a;
}

// ---------------- update MLP: same structure, 16 nodes/tile/wave ----------------
__global__ __launch_bounds__(1024, 4) void upd_kernel(
    const float* __restrict__ h, const float* __restrict__ agg,
    const unsigned short* __restrict__ wts,
    const float* __restrict__ ub1, const float* __restrict__ ub2, const float* __restrict__ ub3,
    const float* __restrict__ ug, const float* __restrict__ ubt,
    float* __restrict__ h_new, int Nn) {
  __shared__ __align__(16) unsigned short lds[73728];   // 147,456 B
  const int tid = threadIdx.x;
  const int w = tid >> 6, lane = tid & 63, quad = lane >> 4, l15 = lane & 15;
  const int sw = l15 & 7;
  const int ntiles = (Nn + 15) >> 4;
  const int stride = gridDim.x * 16;
  int tile = blockIdx.x * 16 + w;

  // prologue prefetch (overlaps weight staging)
  float4 P[8];
  if (tile < ntiles) {
    int n = (tile << 4) + l15; int nc = n < Nn ? n : 0;
    const float* rh = h + (size_t)nc * 64 + quad * 8;
    const float* rg = agg + (size_t)nc * 64 + quad * 8;
    P[0] = *(const float4*)rh;        P[1] = *(const float4*)(rh + 4);
    P[2] = *(const float4*)(rh + 32); P[3] = *(const float4*)(rh + 36);
    P[4] = *(const float4*)rg;        P[5] = *(const float4*)(rg + 4);
    P[6] = *(const float4*)(rg + 32); P[7] = *(const float4*)(rg + 36);
  }

  for (int i = tid; i < 5120; i += 1024)
    *(s16x8*)&lds[i * 8] = *(const s16x8*)&wts[46080 + i * 8];
  __syncthreads();

  unsigned short* act = &lds[40960 + w * 2048];
  const unsigned short* W1 = &lds[0];
  const unsigned short* W2 = &lds[16384];
  const unsigned short* W3 = &lds[32768];

  float b1c[8], b2c[8], b3c[4], gc[4], btc[4];
  #pragma unroll
  for (int nt = 0; nt < 8; nt++) { b1c[nt] = ub1[nt * 16 + l15]; b2c[nt] = ub2[nt * 16 + l15]; }
  #pragma unroll
  for (int nt = 0; nt < 4; nt++) { b3c[nt] = ub3[nt * 16 + l15]; gc[nt] = ug[nt * 16 + l15]; btc[nt] = ubt[nt * 16 + l15]; }

  for (; tile < ntiles; tile += stride) {
    const int n0 = tile << 4;
    s16x8 fa[4];
    fa[0] = cvt8(P[0], P[1]);
    fa[1] = cvt8(P[2], P[3]);
    fa[2] = cvt8(P[4], P[5]);
    fa[3] = cvt8(P[6], P[7]);

    // prefetch next tile (inert at current grid: <=1 tile/wave, kept for generality)
    {
      int tn = tile + stride;
      if (tn < ntiles) {
        int n = (tn << 4) + l15; int nc = n < Nn ? n : 0;
        const float* rh = h + (size_t)nc * 64 + quad * 8;
        const float* rg = agg + (size_t)nc * 64 + quad * 8;
        P[0] = *(const float4*)rh;        P[1] = *(const float4*)(rh + 4);
        P[2] = *(const float4*)(rh + 32); P[3] = *(const float4*)(rh + 36);
        P[4] = *(const float4*)rg;        P[5] = *(const float4*)(rg + 4);
        P[6] = *(const float4*)(rg + 32); P[7] = *(const float4*)(rg + 36);
      }
    }

    f32x4 acc[8];
    #pragma unroll
    for (int nt = 0; nt < 8; nt++) acc[nt] = (f32x4){0.f, 0.f, 0.f, 0.f};
    #pragma unroll
    for (int kb = 0; kb < 4; kb++) {
      int blk8 = (((kb << 2) + quad) ^ sw) << 3;
      #pragma unroll
      for (int nt = 0; nt < 8; nt++) {
        s16x8 b = *(const s16x8*)&W1[(nt * 16 + l15) * 128 + blk8];
        acc[nt] = __builtin_amdgcn_mfma_f32_16x16x32_bf16(fa[kb], b, acc[nt], 0, 0, 0);
      }
    }
    #pragma unroll
    for (int nt = 0; nt < 8; nt++) {
      int cb = 2 * nt + (l15 >> 3);
      #pragma unroll
      for (int r = 0; r < 4; r++) {
        int row = quad * 4 + r;
        float v = acc[nt][r] + b1c[nt];
        v = v > 0.f ? v : 0.f;
        act[row * 128 + ((cb ^ (row & 7)) << 3) + sw] = f2bf(v);
      }
    }

    f32x4 acc2[8];
    #pragma unroll
    for (int nt = 0; nt < 8; nt++) acc2[nt] = (f32x4){0.f, 0.f, 0.f, 0.f};
    #pragma unroll
    for (int kb = 0; kb < 4; kb++) {
      int blk8 = (((kb << 2) + quad) ^ sw) << 3;
      s16x8 a = *(const s16x8*)&act[l15 * 128 + blk8];
      #pragma unroll
      for (int nt = 0; nt < 8; nt++) {
        s16x8 b = *(const s16x8*)&W2[(nt * 16 + l15) * 128 + blk8];
        acc2[nt] = __builtin_amdgcn_mfma_f32_16x16x32_bf16(a, b, acc2[nt], 0, 0, 0);
      }
    }
    #pragma unroll
    for (int nt = 0; nt < 8; nt++) {
      int cb = 2 * nt + (l15 >> 3);
      #pragma unroll
      for (int r = 0; r < 4; r++) {
        int row = quad * 4 + r;
        float v = acc2[nt][r] + b2c[nt];
        v = v > 0.f ? v : 0.f;
        act[row * 128 + ((cb ^ (row & 7)) << 3) + sw] = f2bf(v);
      }
    }

    f32x4 acc3[4];
    #pragma unroll
    for (int nt = 0; nt < 4; nt++) acc3[nt] = (f32x4){0.f, 0.f, 0.f, 0.f};
    #pragma unroll
    for (int kb = 0; kb < 4; kb++) {
      int blk8 = (((kb << 2) + quad) ^ sw) << 3;
      s16x8 a = *(const s16x8*)&act[l15 * 128 + blk8];
      #pragma unroll
      for (int nt = 0; nt < 4; nt++) {
        s16x8 b = *(const s16x8*)&W3[(nt * 16 + l15) * 128 + blk8];
        acc3[nt] = __builtin_amdgcn_mfma_f32_16x16x32_bf16(a, b, acc3[nt], 0, 0, 0);
      }
    }

    #pragma unroll
    for (int r = 0; r < 4; r++) {
      float v0 = acc3[0][r] + b3c[0];
      float v1 = acc3[1][r] + b3c[1];
      float v2 = acc3[2][r] + b3c[2];
      float v3 = acc3[3][r] + b3c[3];
      float p = v0 + v1 + v2 + v3;
      float q = v0 * v0 + v1 * v1 + v2 * v2 + v3 * v3;
      #pragma unroll
      for (int m = 1; m <= 8; m <<= 1) {
        p += __shfl_xor(p, m);
        q += __shfl_xor(q, m);
      }
      float mu = p * (1.f / 64.f);
      float var = q * (1.f / 64.f) - mu * mu;
      float rstd = rsqrtf(var + 1e-5f);
      int row = n0 + quad * 4 + r;
      if (row < Nn) {
        const float* hp = h + (size_t)row * 64 + l15;
        float* op = h_new + (size_t)row * 64 + l15;
        op[0]  = (v0 - mu) * rstd * gc[0] + btc[0] + hp[0];
        op[16] = (v1 - mu) * rstd * gc[1] + btc[1] + hp[16];
        op[32] = (v2 - mu) * rstd * gc[2] + btc[2] + hp[32];
        op[48] = (v3 - mu) * rstd * gc[3] + btc[3] + hp[48];
      }
    }
  }
}

extern "C" void kernel_launch(void* const* d_in, const int* in_sizes, int n_in,
                              void* d_out, int out_size, void* d_ws, size_t ws_size,
                              hipStream_t stream) {
  const float* h   = (const float*)d_in[0];
  const int*   ei  = (const int*)d_in[1];
  const float* ea  = (const float*)d_in[2];
  const float* mW1 = (const float*)d_in[3];
  const float* mb1 = (const float*)d_in[4];
  const float* mW2 = (const float*)d_in[5];
  const float* mb2 = (const float*)d_in[6];
  const float* mW3 = (const float*)d_in[7];
  const float* mb3 = (const float*)d_in[8];
  const float* mg  = (const float*)d_in[9];
  const float* mbt = (const float*)d_in[10];
  const float* uW1 = (const float*)d_in[11];
  const float* ub1 = (const float*)d_in[12];
  const float* uW2 = (const float*)d_in[13];
  const float* ub2 = (const float*)d_in[14];
  const float* uW3 = (const float*)d_in[15];
  const float* ub3 = (const float*)d_in[16];
  const float* ug  = (const float*)d_in[17];
  const float* ubt = (const float*)d_in[18];

  const int N = in_sizes[0] / 64;
  const int E = in_sizes[2] / 32;
  const int* dstI = ei + E;

  char* ws = (char*)d_ws;
  float* agg          = (float*)ws;              ws += (size_t)N * 64 * 4;
  unsigned short* wts = (unsigned short*)ws;     ws += 87040 * 2;
  ws = (char*)(((size_t)ws + 255) & ~(size_t)255);
  int* deg            = (int*)ws;                ws += (size_t)N * 4;
  int* rowptr         = (int*)ws;                ws += (size_t)(N + 1) * 4;
  ws = (char*)(((size_t)ws + 255) & ~(size_t)255);
  int* cursor         = (int*)ws;                ws += (size_t)N * 4;
  ws = (char*)(((size_t)ws + 255) & ~(size_t)255);
  int* csr            = (int*)ws;                ws += (size_t)E * 4;

  float* h_new = (float*)d_out;
  float* msg   = (float*)d_out + (size_t)N * 64;

  hipMemsetAsync(deg, 0, (size_t)N * sizeof(int), stream);
  wconv<<<dim3((86016 + 255) / 256), dim3(256), 0, stream>>>(mW1, mW2, mW3, uW1, uW2, uW3, wts);
  hist_kernel<<<dim3((E + 255) / 256), dim3(256), 0, stream>>>(dstI, deg, E);
  scan_kernel<<<dim3(1), dim3(1024), 0, stream>>>(deg, rowptr, cursor, N);
  scatter_kernel<<<dim3((E + 255) / 256), dim3(256), 0, stream>>>(dstI, cursor, csr, E);
  msg_kernel<<<dim3(256), dim3(1024), 0, stream>>>(
      h, ei, ea, wts, mb1, mb2, mb3, mg, mbt, msg, E);
  agg_kernel<<<dim3((N + 3) / 4), dim3(256), 0, stream>>>(msg, rowptr, csr, agg, N);
  upd_kernel<<<dim3(256), dim3(1024), 0, stream>>>(
      h, agg, wts, ub1, ub2, ub3, ug, ubt, h_new, N);
}

// Round 3
// 552.740 us; speedup vs baseline: 1.0571x; 1.0571x over previous
//
#include <hip/hip_runtime.h>
#include <hip/hip_bf16.h>

// EdgeConv fused GNN. R7 (= R6 de-risked): pipeline kept, spill eliminated.
// - amdgpu_waves_per_eu(4,4) on MLP kernels: LDS already caps at 4 waves/EU,
//   so giving the RA the full 128-VGPR budget is free -> P[] stays in registers.
// - Bias/gain constants in spare LDS (transposed, padded; conflict-free b128 reloads).
// - LayerNorm reduce via proven __shfl_xor butterfly (DPP variant deferred).
// - Aggregation by CSR gather, quad-per-edge float4 loads.

typedef __attribute__((ext_vector_type(8))) short s16x8;   // MFMA A/B frag (8 bf16)
typedef __attribute__((ext_vector_type(4))) float f32x4;   // MFMA C/D frag

__device__ __forceinline__ unsigned short f2bf(float x) {
  union { float f; unsigned u; } v; v.f = x;
  unsigned r = v.u + 0x7fffu + ((v.u >> 16) & 1u);   // RNE
  return (unsigned short)(r >> 16);
}

// pack 8 fp32 (two float4) -> bf16 frag
__device__ __forceinline__ s16x8 cvt8(float4 a, float4 b) {
  union { s16x8 v; __hip_bfloat162 h2[4]; } u;
  float2 t;
  t.x = a.x; t.y = a.y; u.h2[0] = __float22bfloat162_rn(t);
  t.x = a.z; t.y = a.w; u.h2[1] = __float22bfloat162_rn(t);
  t.x = b.x; t.y = b.y; u.h2[2] = __float22bfloat162_rn(t);
  t.x = b.z; t.y = b.w; u.h2[3] = __float22bfloat162_rn(t);
  return u.v;
}

// ---------------- weight transpose+convert into final (swizzled) layout ----------------
// ushort offsets in wts:
//  mW1t @0     : 128 rows x stride 168 (k<160, unswizzled; pad never read)
//  mW2t @21504 : 128 x 128, XOR-swizzled
//  mW3t @37888 :  64 x 128, XOR-swizzled
//  uW1t @46080 : 128 x 128, uW2t @62464, uW3t @78848 (64x128); total 87040 ushorts
__global__ __launch_bounds__(256) void wconv(
    const float* __restrict__ mW1, const float* __restrict__ mW2, const float* __restrict__ mW3,
    const float* __restrict__ uW1, const float* __restrict__ uW2, const float* __restrict__ uW3,
    unsigned short* __restrict__ wts) {
  int t = blockIdx.x * 256 + threadIdx.x;
  const float* src; int K, N, off, base;
  if      (t < 20480) { src = mW1; K = 160; N = 128; off = 0;     base = 0;     }
  else if (t < 36864) { src = mW2; K = 128; N = 128; off = 20480; base = 21504; }
  else if (t < 45056) { src = mW3; K = 128; N = 64;  off = 36864; base = 37888; }
  else if (t < 61440) { src = uW1; K = 128; N = 128; off = 45056; base = 46080; }
  else if (t < 77824) { src = uW2; K = 128; N = 128; off = 61440; base = 62464; }
  else if (t < 86016) { src = uW3; K = 128; N = 64;  off = 77824; base = 78848; }
  else return;
  int local = t - off;
  int n = local / K, k = local - n * K;
  int idx;
  if (K == 160) idx = n * 168 + k;                                        // mW1t: padded, plain
  else          idx = base + n * 128 + ((((k >> 3) ^ (n & 7)) << 3) | (k & 7));
  wts[idx] = f2bf(src[k * N + n]);
}

// ---------------- CSR build ----------------
__global__ __launch_bounds__(256) void hist_kernel(const int* __restrict__ dstI,
                                                   int* __restrict__ deg, int E) {
  int t = blockIdx.x * 256 + threadIdx.x;
  if (t < E) atomicAdd(&deg[dstI[t]], 1);
}

__global__ __launch_bounds__(1024) void scan_kernel(const int* __restrict__ deg,
                                                    int* __restrict__ rowptr,
                                                    int* __restrict__ cursor, int Nn) {
  __shared__ int part[1024], offs[1024];
  int t = threadIdx.x;
  int C = (Nn + 1023) / 1024;
  int lo = t * C, hi = lo + C < Nn ? lo + C : Nn;
  int sum = 0;
  for (int i = lo; i < hi; i++) sum += deg[i];
  part[t] = sum;
  __syncthreads();
  if (t == 0) {
    int run = 0;
    for (int i = 0; i < 1024; i++) { offs[i] = run; run += part[i]; }
  }
  __syncthreads();
  int run = offs[t];
  for (int i = lo; i < hi; i++) { rowptr[i] = run; cursor[i] = run; run += deg[i]; }
  if (t == 1023) rowptr[Nn] = offs[1023] + part[1023];
}

__global__ __launch_bounds__(256) void scatter_kernel(const int* __restrict__ dstI,
                                                      int* __restrict__ cursor,
                                                      int* __restrict__ csr, int E) {
  int t = blockIdx.x * 256 + threadIdx.x;
  if (t < E) {
    int pos = atomicAdd(&cursor[dstI[t]], 1);
    csr[pos] = t;
  }
}

// bias LDS layout (floats, from bias base):
//  b1 @0   : [l15*12 + nt] nt<8  (stride 12 for b128 alignment + bank spread)
//  b2 @192 : same
//  b3 @384, g @448, bt @512 : [l15*4 + nt] nt<4
// total 576 floats = 2304 B
__device__ __forceinline__ void stage_bias(float* bf, int tid, int nthr,
    const float* b1, const float* b2, const float* b3,
    const float* g, const float* bt) {
  for (int i = tid; i < 576; i += nthr) {
    float v = 0.f;
    if (i < 192)      { int c = i;       int l = c / 12, nt = c % 12; if (nt < 8) v = b1[nt * 16 + l]; }
    else if (i < 384) { int c = i - 192; int l = c / 12, nt = c % 12; if (nt < 8) v = b2[nt * 16 + l]; }
    else if (i < 448) { int c = i - 384; int l = c / 4,  nt = c % 4;  v = b3[nt * 16 + l]; }
    else if (i < 512) { int c = i - 448; int l = c / 4,  nt = c % 4;  v = g[nt * 16 + l]; }
    else              { int c = i - 512; int l = c / 4,  nt = c % 4;  v = bt[nt * 16 + l]; }
    bf[i] = v;
  }
}

// ---------------- message MLP: persistent blocks, 16 waves, 16 edges/tile/wave ----------------
__global__ __attribute__((amdgpu_flat_work_group_size(1024, 1024), amdgpu_waves_per_eu(4, 4)))
void msg_kernel(
    const float* __restrict__ h, const int* __restrict__ ei, const float* __restrict__ ea,
    const unsigned short* __restrict__ wts,
    const float* __restrict__ mb1, const float* __restrict__ mb2, const float* __restrict__ mb3,
    const float* __restrict__ mg, const float* __restrict__ mbt,
    float* __restrict__ msg_out, int E) {
  __shared__ __align__(16) unsigned short lds[80000];   // 160,000 B
  const int tid = threadIdx.x;
  const int w = tid >> 6, lane = tid & 63, quad = lane >> 4, l15 = lane & 15;
  const int sw = l15 & 7;
  const int* srcI = ei;
  const int* dstI = ei + E;
  const int ntiles = (E + 15) >> 4;
  const int stride = gridDim.x * 16;
  int tile = blockIdx.x * 16 + w;

  // ---- prologue: issue first tile's gathers BEFORE staging (latency rides under it)
  float4 P[10];
  int sN = 0, dN = 0;
  if (tile < ntiles) {
    int e = (tile << 4) + l15; int ec = e < E ? e : E - 1;
    int s = srcI[ec], d = dstI[ec];
    const float* rs = h + (size_t)s * 64 + quad * 8;
    const float* rd = h + (size_t)d * 64 + quad * 8;
    const float* re = ea + (size_t)ec * 32 + quad * 8;
    P[0] = *(const float4*)rs;        P[1] = *(const float4*)(rs + 4);
    P[2] = *(const float4*)(rs + 32); P[3] = *(const float4*)(rs + 36);
    P[4] = *(const float4*)rd;        P[5] = *(const float4*)(rd + 4);
    P[6] = *(const float4*)(rd + 32); P[7] = *(const float4*)(rd + 36);
    P[8] = *(const float4*)re;        P[9] = *(const float4*)(re + 4);
    int tn = tile + stride;
    if (tn < ntiles) {
      int e2 = (tn << 4) + l15; int ec2 = e2 < E ? e2 : E - 1;
      sN = srcI[ec2]; dN = dstI[ec2];
    }
  }

  // stage all msg weights (46080 ushorts) + biases once
  for (int i = tid; i < 5760; i += 1024)
    *(s16x8*)&lds[i * 8] = *(const s16x8*)&wts[i * 8];
  float* bf = (float*)&lds[78848];
  stage_bias(bf, tid, 1024, mb1, mb2, mb3, mg, mbt);
  __syncthreads();

  unsigned short* act = &lds[46080 + w * 2048];         // per-wave 4KB, swizzled, stride 128
  const unsigned short* W1 = &lds[0];
  const unsigned short* W2 = &lds[21504];
  const unsigned short* W3 = &lds[37888];

  for (; tile < ntiles; tile += stride) {
    const int e0 = tile << 4;

    // consume prefetched rows (waits on the loads issued a full tile ago)
    s16x8 fa[5];
    fa[0] = cvt8(P[0], P[1]);
    fa[1] = cvt8(P[2], P[3]);
    fa[2] = cvt8(P[4], P[5]);
    fa[3] = cvt8(P[6], P[7]);
    fa[4] = cvt8(P[8], P[9]);

    // ---- L1: 160 -> 128, B from LDS (stride 168, conflict-free)
    f32x4 acc[8];
    #pragma unroll
    for (int nt = 0; nt < 8; nt++) acc[nt] = (f32x4){0.f, 0.f, 0.f, 0.f};
    #pragma unroll
    for (int kb = 0; kb < 5; kb++) {
      #pragma unroll
      for (int nt = 0; nt < 8; nt++) {
        s16x8 b = *(const s16x8*)&W1[(nt * 16 + l15) * 168 + kb * 32 + quad * 8];
        acc[nt] = __builtin_amdgcn_mfma_f32_16x16x32_bf16(fa[kb], b, acc[nt], 0, 0, 0);
      }
    }
    // act1 = relu(acc + b1), bf16, swizzled (col = nt*16+l15 -> block 2nt+(l15>>3))
    {
      union { float4 v[2]; float f[8]; } b1u;
      b1u.v[0] = *(const float4*)&bf[l15 * 12];
      b1u.v[1] = *(const float4*)&bf[l15 * 12 + 4];
      #pragma unroll
      for (int nt = 0; nt < 8; nt++) {
        int cb = 2 * nt + (l15 >> 3);
        #pragma unroll
        for (int r = 0; r < 4; r++) {
          int row = quad * 4 + r;
          float v = acc[nt][r] + b1u.f[nt];
          v = v > 0.f ? v : 0.f;
          act[row * 128 + ((cb ^ (row & 7)) << 3) + sw] = f2bf(v);
        }
      }
    }

    // ---- prefetch next tile's rows (fa dead; P regs refill). Latency hides under L2+L3+LN.
    {
      int tn = tile + stride;
      if (tn < ntiles) {
        const float* rs = h + (size_t)sN * 64 + quad * 8;
        const float* rd = h + (size_t)dN * 64 + quad * 8;
        int en = (tn << 4) + l15; int ecn = en < E ? en : E - 1;
        const float* re = ea + (size_t)ecn * 32 + quad * 8;
        P[0] = *(const float4*)rs;        P[1] = *(const float4*)(rs + 4);
        P[2] = *(const float4*)(rs + 32); P[3] = *(const float4*)(rs + 36);
        P[4] = *(const float4*)rd;        P[5] = *(const float4*)(rd + 4);
        P[6] = *(const float4*)(rd + 32); P[7] = *(const float4*)(rd + 36);
        P[8] = *(const float4*)re;        P[9] = *(const float4*)(re + 4);
        int tn2 = tn + stride;
        if (tn2 < ntiles) {
          int e2 = (tn2 << 4) + l15; int ec2 = e2 < E ? e2 : E - 1;
          sN = srcI[ec2]; dN = dstI[ec2];
        }
      }
    }

    // ---- L2: 128 -> 128 (A from act, B from W2; both swizzled stride 128)
    f32x4 acc2[8];
    #pragma unroll
    for (int nt = 0; nt < 8; nt++) acc2[nt] = (f32x4){0.f, 0.f, 0.f, 0.f};
    #pragma unroll
    for (int kb = 0; kb < 4; kb++) {
      int blk8 = (((kb << 2) + quad) ^ sw) << 3;
      s16x8 a = *(const s16x8*)&act[l15 * 128 + blk8];
      #pragma unroll
      for (int nt = 0; nt < 8; nt++) {
        s16x8 b = *(const s16x8*)&W2[(nt * 16 + l15) * 128 + blk8];
        acc2[nt] = __builtin_amdgcn_mfma_f32_16x16x32_bf16(a, b, acc2[nt], 0, 0, 0);
      }
    }
    {
      union { float4 v[2]; float f[8]; } b2u;
      b2u.v[0] = *(const float4*)&bf[192 + l15 * 12];
      b2u.v[1] = *(const float4*)&bf[192 + l15 * 12 + 4];
      #pragma unroll
      for (int nt = 0; nt < 8; nt++) {
        int cb = 2 * nt + (l15 >> 3);
        #pragma unroll
        for (int r = 0; r < 4; r++) {
          int row = quad * 4 + r;
          float v = acc2[nt][r] + b2u.f[nt];
          v = v > 0.f ? v : 0.f;
          act[row * 128 + ((cb ^ (row & 7)) << 3) + sw] = f2bf(v);
        }
      }
    }

    // ---- L3: 128 -> 64
    f32x4 acc3[4];
    #pragma unroll
    for (int nt = 0; nt < 4; nt++) acc3[nt] = (f32x4){0.f, 0.f, 0.f, 0.f};
    #pragma unroll
    for (int kb = 0; kb < 4; kb++) {
      int blk8 = (((kb << 2) + quad) ^ sw) << 3;
      s16x8 a = *(const s16x8*)&act[l15 * 128 + blk8];
      #pragma unroll
      for (int nt = 0; nt < 4; nt++) {
        s16x8 b = *(const s16x8*)&W3[(nt * 16 + l15) * 128 + blk8];
        acc3[nt] = __builtin_amdgcn_mfma_f32_16x16x32_bf16(a, b, acc3[nt], 0, 0, 0);
      }
    }

    // ---- LayerNorm in registers (rows = quad*4+r, cols nt*16+l15) + store
    {
      union { float4 v; float f[4]; } b3u, gu, btu;
      b3u.v = *(const float4*)&bf[384 + l15 * 4];
      gu.v  = *(const float4*)&bf[448 + l15 * 4];
      btu.v = *(const float4*)&bf[512 + l15 * 4];
      #pragma unroll
      for (int r = 0; r < 4; r++) {
        float v0 = acc3[0][r] + b3u.f[0];
        float v1 = acc3[1][r] + b3u.f[1];
        float v2 = acc3[2][r] + b3u.f[2];
        float v3 = acc3[3][r] + b3u.f[3];
        float p = v0 + v1 + v2 + v3;
        float q = v0 * v0 + v1 * v1 + v2 * v2 + v3 * v3;
        #pragma unroll
        for (int m = 1; m <= 8; m <<= 1) {
          p += __shfl_xor(p, m);
          q += __shfl_xor(q, m);
        }
        float mu = p * (1.f / 64.f);
        float var = q * (1.f / 64.f) - mu * mu;
        float rstd = rsqrtf(var + 1e-5f);
        int row = e0 + quad * 4 + r;
        if (row < E) {
          float* mp = msg_out + (size_t)row * 64 + l15;
          mp[0]  = (v0 - mu) * rstd * gu.f[0] + btu.f[0];
          mp[16] = (v1 - mu) * rstd * gu.f[1] + btu.f[1];
          mp[32] = (v2 - mu) * rstd * gu.f[2] + btu.f[2];
          mp[48] = (v3 - mu) * rstd * gu.f[3] + btu.f[3];
        }
      }
    }
  }
}

// ---------------- aggregation by gather: one node per wave, quad-per-edge float4 ----------------
__global__ __launch_bounds__(256) void agg_kernel(
    const float* __restrict__ msg, const int* __restrict__ rowptr,
    const int* __restrict__ csr, float* __restrict__ agg, int Nn) {
  int node = (blockIdx.x * 256 + threadIdx.x) >> 6;
  int lane = threadIdx.x & 63;
  int eo = lane >> 4, l = lane & 15;
  if (node >= Nn) return;
  int s = rowptr[node], e = rowptr[node + 1];
  float4 a = {0.f, 0.f, 0.f, 0.f};
  for (int j = s + eo; j < e; j += 4) {
    const float4 m = *(const float4*)&msg[(size_t)csr[j] * 64 + l * 4];
    a.x += m.x; a.y += m.y; a.z += m.z; a.w += m.w;
  }
  // reduce the 4 quads
  a.x += __shfl_xor(a.x, 16); a.y += __shfl_xor(a.y, 16);
  a.z += __shfl_xor(a.z, 16); a.w += __shfl_xor(a.w, 16);
  a.x += __shfl_xor(a.x, 32); a.y += __shfl_xor(a.y, 32);
  a.z += __shfl_xor(a.z, 32); a.w += __shfl_xor(a.w, 32);
  if (eo == 0) *(float4*)&agg[(size_t)node * 64 + l * 4] = a;
}

// ---------------- update MLP: same structure, 16 nodes/tile/wave ----------------
__global__ __attribute__((amdgpu_flat_work_group_size(1024, 1024), amdgpu_waves_per_eu(4, 4)))
void upd_kernel(
    const float* __restrict__ h, const float* __restrict__ agg,
    const unsigned short* __restrict__ wts,
    const float* __restrict__ ub1, const float* __restrict__ ub2, const float* __restrict__ ub3,
    const float* __restrict__ ug, const float* __restrict__ ubt,
    float* __restrict__ h_new, int Nn) {
  __shared__ __align__(16) unsigned short lds[74880];   // 149,760 B
  const int tid = threadIdx.x;
  const int w = tid >> 6, lane = tid & 63, quad = lane >> 4, l15 = lane & 15;
  const int sw = l15 & 7;
  const int ntiles = (Nn + 15) >> 4;
  const int stride = gridDim.x * 16;
  int tile = blockIdx.x * 16 + w;

  // prologue prefetch (overlaps weight staging)
  float4 P[8];
  if (tile < ntiles) {
    int n = (tile << 4) + l15; int nc = n < Nn ? n : 0;
    const float* rh = h + (size_t)nc * 64 + quad * 8;
    const float* rg = agg + (size_t)nc * 64 + quad * 8;
    P[0] = *(const float4*)rh;        P[1] = *(const float4*)(rh + 4);
    P[2] = *(const float4*)(rh + 32); P[3] = *(const float4*)(rh + 36);
    P[4] = *(const float4*)rg;        P[5] = *(const float4*)(rg + 4);
    P[6] = *(const float4*)(rg + 32); P[7] = *(const float4*)(rg + 36);
  }

  for (int i = tid; i < 5120; i += 1024)
    *(s16x8*)&lds[i * 8] = *(const s16x8*)&wts[46080 + i * 8];
  float* bf = (float*)&lds[73728];
  stage_bias(bf, tid, 1024, ub1, ub2, ub3, ug, ubt);
  __syncthreads();

  unsigned short* act = &lds[40960 + w * 2048];
  const unsigned short* W1 = &lds[0];
  const unsigned short* W2 = &lds[16384];
  const unsigned short* W3 = &lds[32768];

  for (; tile < ntiles; tile += stride) {
    const int n0 = tile << 4;
    s16x8 fa[4];
    fa[0] = cvt8(P[0], P[1]);
    fa[1] = cvt8(P[2], P[3]);
    fa[2] = cvt8(P[4], P[5]);
    fa[3] = cvt8(P[6], P[7]);

    // prefetch next tile (inert at current grid: <=1 tile/wave, kept for generality)
    {
      int tn = tile + stride;
      if (tn < ntiles) {
        int n = (tn << 4) + l15; int nc = n < Nn ? n : 0;
        const float* rh = h + (size_t)nc * 64 + quad * 8;
        const float* rg = agg + (size_t)nc * 64 + quad * 8;
        P[0] = *(const float4*)rh;        P[1] = *(const float4*)(rh + 4);
        P[2] = *(const float4*)(rh + 32); P[3] = *(const float4*)(rh + 36);
        P[4] = *(const float4*)rg;        P[5] = *(const float4*)(rg + 4);
        P[6] = *(const float4*)(rg + 32); P[7] = *(const float4*)(rg + 36);
      }
    }

    f32x4 acc[8];
    #pragma unroll
    for (int nt = 0; nt < 8; nt++) acc[nt] = (f32x4){0.f, 0.f, 0.f, 0.f};
    #pragma unroll
    for (int kb = 0; kb < 4; kb++) {
      int blk8 = (((kb << 2) + quad) ^ sw) << 3;
      #pragma unroll
      for (int nt = 0; nt < 8; nt++) {
        s16x8 b = *(const s16x8*)&W1[(nt * 16 + l15) * 128 + blk8];
        acc[nt] = __builtin_amdgcn_mfma_f32_16x16x32_bf16(fa[kb], b, acc[nt], 0, 0, 0);
      }
    }
    {
      union { float4 v[2]; float f[8]; } b1u;
      b1u.v[0] = *(const float4*)&bf[l15 * 12];
      b1u.v[1] = *(const float4*)&bf[l15 * 12 + 4];
      #pragma unroll
      for (int nt = 0; nt < 8; nt++) {
        int cb = 2 * nt + (l15 >> 3);
        #pragma unroll
        for (int r = 0; r < 4; r++) {
          int row = quad * 4 + r;
          float v = acc[nt][r] + b1u.f[nt];
          v = v > 0.f ? v : 0.f;
          act[row * 128 + ((cb ^ (row & 7)) << 3) + sw] = f2bf(v);
        }
      }
    }

    f32x4 acc2[8];
    #pragma unroll
    for (int nt = 0; nt < 8; nt++) acc2[nt] = (f32x4){0.f, 0.f, 0.f, 0.f};
    #pragma unroll
    for (int kb = 0; kb < 4; kb++) {
      int blk8 = (((kb << 2) + quad) ^ sw) << 3;
      s16x8 a = *(const s16x8*)&act[l15 * 128 + blk8];
      #pragma unroll
      for (int nt = 0; nt < 8; nt++) {
        s16x8 b = *(const s16x8*)&W2[(nt * 16 + l15) * 128 + blk8];
        acc2[nt] = __builtin_amdgcn_mfma_f32_16x16x32_bf16(a, b, acc2[nt], 0, 0, 0);
      }
    }
    {
      union { float4 v[2]; float f[8]; } b2u;
      b2u.v[0] = *(const float4*)&bf[192 + l15 * 12];
      b2u.v[1] = *(const float4*)&bf[192 + l15 * 12 + 4];
      #pragma unroll
      for (int nt = 0; nt < 8; nt++) {
        int cb = 2 * nt + (l15 >> 3);
        #pragma unroll
        for (int r = 0; r < 4; r++) {
          int row = quad * 4 + r;
          float v = acc2[nt][r] + b2u.f[nt];
          v = v > 0.f ? v : 0.f;
          act[row * 128 + ((cb ^ (row & 7)) << 3) + sw] = f2bf(v);
        }
      }
    }

    f32x4 acc3[4];
    #pragma unroll
    for (int nt = 0; nt < 4; nt++) acc3[nt] = (f32x4){0.f, 0.f, 0.f, 0.f};
    #pragma unroll
    for (int kb = 0; kb < 4; kb++) {
      int blk8 = (((kb << 2) + quad) ^ sw) << 3;
      s16x8 a = *(const s16x8*)&act[l15 * 128 + blk8];
      #pragma unroll
      for (int nt = 0; nt < 4; nt++) {
        s16x8 b = *(const s16x8*)&W3[(nt * 16 + l15) * 128 + blk8];
        acc3[nt] = __builtin_amdgcn_mfma_f32_16x16x32_bf16(a, b, acc3[nt], 0, 0, 0);
      }
    }

    {
      union { float4 v; float f[4]; } b3u, gu, btu;
      b3u.v = *(const float4*)&bf[384 + l15 * 4];
      gu.v  = *(const float4*)&bf[448 + l15 * 4];
      btu.v = *(const float4*)&bf[512 + l15 * 4];
      #pragma unroll
      for (int r = 0; r < 4; r++) {
        float v0 = acc3[0][r] + b3u.f[0];
        float v1 = acc3[1][r] + b3u.f[1];
        float v2 = acc3[2][r] + b3u.f[2];
        float v3 = acc3[3][r] + b3u.f[3];
        float p = v0 + v1 + v2 + v3;
        float q = v0 * v0 + v1 * v1 + v2 * v2 + v3 * v3;
        #pragma unroll
        for (int m = 1; m <= 8; m <<= 1) {
          p += __shfl_xor(p, m);
          q += __shfl_xor(q, m);
        }
        float mu = p * (1.f / 64.f);
        float var = q * (1.f / 64.f) - mu * mu;
        float rstd = rsqrtf(var + 1e-5f);
        int row = n0 + quad * 4 + r;
        if (row < Nn) {
          const float* hp = h + (size_t)row * 64 + l15;
          float* op = h_new + (size_t)row * 64 + l15;
          op[0]  = (v0 - mu) * rstd * gu.f[0] + btu.f[0] + hp[0];
          op[16] = (v1 - mu) * rstd * gu.f[1] + btu.f[1] + hp[16];
          op[32] = (v2 - mu) * rstd * gu.f[2] + btu.f[2] + hp[32];
          op[48] = (v3 - mu) * rstd * gu.f[3] + btu.f[3] + hp[48];
        }
      }
    }
  }
}

extern "C" void kernel_launch(void* const* d_in, const int* in_sizes, int n_in,
                              void* d_out, int out_size, void* d_ws, size_t ws_size,
                              hipStream_t stream) {
  const float* h   = (const float*)d_in[0];
  const int*   ei  = (const int*)d_in[1];
  const float* ea  = (const float*)d_in[2];
  const float* mW1 = (const float*)d_in[3];
  const float* mb1 = (const float*)d_in[4];
  const float* mW2 = (const float*)d_in[5];
  const float* mb2 = (const float*)d_in[6];
  const float* mW3 = (const float*)d_in[7];
  const float* mb3 = (const float*)d_in[8];
  const float* mg  = (const float*)d_in[9];
  const float* mbt = (const float*)d_in[10];
  const float* uW1 = (const float*)d_in[11];
  const float* ub1 = (const float*)d_in[12];
  const float* uW2 = (const float*)d_in[13];
  const float* ub2 = (const float*)d_in[14];
  const float* uW3 = (const float*)d_in[15];
  const float* ub3 = (const float*)d_in[16];
  const float* ug  = (const float*)d_in[17];
  const float* ubt = (const float*)d_in[18];

  const int N = in_sizes[0] / 64;
  const int E = in_sizes[2] / 32;
  const int* dstI = ei + E;

  char* ws = (char*)d_ws;
  float* agg          = (float*)ws;              ws += (size_t)N * 64 * 4;
  unsigned short* wts = (unsigned short*)ws;     ws += 87040 * 2;
  ws = (char*)(((size_t)ws + 255) & ~(size_t)255);
  int* deg            = (int*)ws;                ws += (size_t)N * 4;
  int* rowptr         = (int*)ws;                ws += (size_t)(N + 1) * 4;
  ws = (char*)(((size_t)ws + 255) & ~(size_t)255);
  int* cursor         = (int*)ws;                ws += (size_t)N * 4;
  ws = (char*)(((size_t)ws + 255) & ~(size_t)255);
  int* csr            = (int*)ws;                ws += (size_t)E * 4;

  float* h_new = (float*)d_out;
  float* msg   = (float*)d_out + (size_t)N * 64;

  hipMemsetAsync(deg, 0, (size_t)N * sizeof(int), stream);
  wconv<<<dim3((86016 + 255) / 256), dim3(256), 0, stream>>>(mW1, mW2, mW3, uW1, uW2, uW3, wts);
  hist_kernel<<<dim3((E + 255) / 256), dim3(256), 0, stream>>>(dstI, deg, E);
  scan_kernel<<<dim3(1), dim3(1024), 0, stream>>>(deg, rowptr, cursor, N);
  scatter_kernel<<<dim3((E + 255) / 256), dim3(256), 0, stream>>>(dstI, cursor, csr, E);
  msg_kernel<<<dim3(256), dim3(1024), 0, stream>>>(
      h, ei, ea, wts, mb1, mb2, mb3, mg, mbt, msg, E);
  agg_kernel<<<dim3((N + 3) / 4), dim3(256), 0, stream>>>(msg, rowptr, csr, agg, N);
  upd_kernel<<<dim3(256), dim3(1024), 0, stream>>>(
      h, agg, wts, ub1, ub2, ub3, ug, ubt, h_new, N);
}

// Round 4
// 488.121 us; speedup vs baseline: 1.1970x; 1.1324x over previous
//
#include <hip/hip_runtime.h>
#include <hip/hip_bf16.h>

// EdgeConv fused GNN. R8: msg_kernel reworked for the measured 64V+64A register split.
// - msg: 512 threads / 8 waves, 32 edges per wave-tile. Each LDS B-fragment read
//   feeds TWO MFMAs (edge groups 1/2) -> per-edge weight-read LDS traffic ~halved.
//   VGPR side (fa1+fa2+addr ~55) fits the 64-arch-VGPR cap; dual accumulators
//   (<=64 f32) live in the AGPR half. No register prefetch pipeline (it spills).
// - act buffer 8 KB/wave (32 rows x 128), XOR swizzle extended with (row>>3)<<2.
// - Bias/gain constants in spare LDS; LayerNorm via __shfl_xor butterfly.
// - upd/agg/CSR kernels unchanged (R7-verified).

typedef __attribute__((ext_vector_type(8))) short s16x8;   // MFMA A/B frag (8 bf16)
typedef __attribute__((ext_vector_type(4))) float f32x4;   // MFMA C/D frag

__device__ __forceinline__ unsigned short f2bf(float x) {
  union { float f; unsigned u; } v; v.f = x;
  unsigned r = v.u + 0x7fffu + ((v.u >> 16) & 1u);   // RNE
  return (unsigned short)(r >> 16);
}

__device__ __forceinline__ s16x8 ld_cvt8(const float* p) {
  float4 a = *(const float4*)p;
  float4 b = *(const float4*)(p + 4);
  union { s16x8 v; __hip_bfloat162 h2[4]; } u;
  float2 t;
  t.x = a.x; t.y = a.y; u.h2[0] = __float22bfloat162_rn(t);
  t.x = a.z; t.y = a.w; u.h2[1] = __float22bfloat162_rn(t);
  t.x = b.x; t.y = b.y; u.h2[2] = __float22bfloat162_rn(t);
  t.x = b.z; t.y = b.w; u.h2[3] = __float22bfloat162_rn(t);
  return u.v;
}

// ---------------- weight transpose+convert into final (swizzled) layout ----------------
// ushort offsets in wts:
//  mW1t @0     : 128 rows x stride 168 (k<160, unswizzled; pad never read)
//  mW2t @21504 : 128 x 128, XOR-swizzled
//  mW3t @37888 :  64 x 128, XOR-swizzled
//  uW1t @46080 : 128 x 128, uW2t @62464, uW3t @78848 (64x128); total 87040 ushorts
__global__ __launch_bounds__(256) void wconv(
    const float* __restrict__ mW1, const float* __restrict__ mW2, const float* __restrict__ mW3,
    const float* __restrict__ uW1, const float* __restrict__ uW2, const float* __restrict__ uW3,
    unsigned short* __restrict__ wts) {
  int t = blockIdx.x * 256 + threadIdx.x;
  const float* src; int K, N, off, base;
  if      (t < 20480) { src = mW1; K = 160; N = 128; off = 0;     base = 0;     }
  else if (t < 36864) { src = mW2; K = 128; N = 128; off = 20480; base = 21504; }
  else if (t < 45056) { src = mW3; K = 128; N = 64;  off = 36864; base = 37888; }
  else if (t < 61440) { src = uW1; K = 128; N = 128; off = 45056; base = 46080; }
  else if (t < 77824) { src = uW2; K = 128; N = 128; off = 61440; base = 62464; }
  else if (t < 86016) { src = uW3; K = 128; N = 64;  off = 77824; base = 78848; }
  else return;
  int local = t - off;
  int n = local / K, k = local - n * K;
  int idx;
  if (K == 160) idx = n * 168 + k;                                        // mW1t: padded, plain
  else          idx = base + n * 128 + ((((k >> 3) ^ (n & 7)) << 3) | (k & 7));
  wts[idx] = f2bf(src[k * N + n]);
}

// ---------------- CSR build ----------------
__global__ __launch_bounds__(256) void hist_kernel(const int* __restrict__ dstI,
                                                   int* __restrict__ deg, int E) {
  int t = blockIdx.x * 256 + threadIdx.x;
  if (t < E) atomicAdd(&deg[dstI[t]], 1);
}

__global__ __launch_bounds__(1024) void scan_kernel(const int* __restrict__ deg,
                                                    int* __restrict__ rowptr,
                                                    int* __restrict__ cursor, int Nn) {
  __shared__ int part[1024], offs[1024];
  int t = threadIdx.x;
  int C = (Nn + 1023) / 1024;
  int lo = t * C, hi = lo + C < Nn ? lo + C : Nn;
  int sum = 0;
  for (int i = lo; i < hi; i++) sum += deg[i];
  part[t] = sum;
  __syncthreads();
  if (t == 0) {
    int run = 0;
    for (int i = 0; i < 1024; i++) { offs[i] = run; run += part[i]; }
  }
  __syncthreads();
  int run = offs[t];
  for (int i = lo; i < hi; i++) { rowptr[i] = run; cursor[i] = run; run += deg[i]; }
  if (t == 1023) rowptr[Nn] = offs[1023] + part[1023];
}

__global__ __launch_bounds__(256) void scatter_kernel(const int* __restrict__ dstI,
                                                      int* __restrict__ cursor,
                                                      int* __restrict__ csr, int E) {
  int t = blockIdx.x * 256 + threadIdx.x;
  if (t < E) {
    int pos = atomicAdd(&cursor[dstI[t]], 1);
    csr[pos] = t;
  }
}

// bias LDS layout (floats, from bias base):
//  b1 @0   : [l15*12 + nt] nt<8  (stride 12 for b128 alignment + bank spread)
//  b2 @192 : same
//  b3 @384, g @448, bt @512 : [l15*4 + nt] nt<4
__device__ __forceinline__ void stage_bias(float* bf, int tid, int nthr,
    const float* b1, const float* b2, const float* b3,
    const float* g, const float* bt) {
  for (int i = tid; i < 576; i += nthr) {
    float v = 0.f;
    if (i < 192)      { int c = i;       int l = c / 12, nt = c % 12; if (nt < 8) v = b1[nt * 16 + l]; }
    else if (i < 384) { int c = i - 192; int l = c / 12, nt = c % 12; if (nt < 8) v = b2[nt * 16 + l]; }
    else if (i < 448) { int c = i - 384; int l = c / 4,  nt = c % 4;  v = b3[nt * 16 + l]; }
    else if (i < 512) { int c = i - 448; int l = c / 4,  nt = c % 4;  v = g[nt * 16 + l]; }
    else              { int c = i - 512; int l = c / 4,  nt = c % 4;  v = bt[nt * 16 + l]; }
    bf[i] = v;
  }
}

// ---------------- message MLP: 8 waves, 32 edges/tile/wave, dual-group accumulate ----------------
__global__ __attribute__((amdgpu_flat_work_group_size(512, 512), amdgpu_waves_per_eu(4, 4)))
void msg_kernel(
    const float* __restrict__ h, const int* __restrict__ ei, const float* __restrict__ ea,
    const unsigned short* __restrict__ wts,
    const float* __restrict__ mb1, const float* __restrict__ mb2, const float* __restrict__ mb3,
    const float* __restrict__ mg, const float* __restrict__ mbt,
    float* __restrict__ msg_out, int E) {
  __shared__ __align__(16) unsigned short lds[80000];   // 160,000 B
  const int tid = threadIdx.x;
  const int w = tid >> 6, lane = tid & 63, quad = lane >> 4, l15 = lane & 15;
  const int sw = l15 & 7;
  const int* srcI = ei;
  const int* dstI = ei + E;
  const int ntiles = (E + 31) >> 5;
  const int stride = gridDim.x * 8;
  int tile = blockIdx.x * 8 + w;

  // stage all msg weights (46080 ushorts) + biases once
  for (int i = tid; i < 5760; i += 512)
    *(s16x8*)&lds[i * 8] = *(const s16x8*)&wts[i * 8];
  float* bf = (float*)&lds[78848];
  stage_bias(bf, tid, 512, mb1, mb2, mb3, mg, mbt);
  __syncthreads();

  unsigned short* act = &lds[46080 + w * 4096];   // per-wave 8KB: 32 rows x 128, swizzled
  const unsigned short* W1 = &lds[0];
  const unsigned short* W2 = &lds[21504];
  const unsigned short* W3 = &lds[37888];

  for (; tile < ntiles; tile += stride) {
    const int e0 = tile << 5;
    // ---- gather both 16-edge groups' A-fragments
    int ep1 = e0 + l15, ep2 = e0 + 16 + l15;
    int ec1 = ep1 < E ? ep1 : E - 1;
    int ec2 = ep2 < E ? ep2 : E - 1;
    int s1 = srcI[ec1], d1 = dstI[ec1];
    int s2 = srcI[ec2], d2 = dstI[ec2];
    const float* rs1 = h + (size_t)s1 * 64 + quad * 8;
    const float* rd1 = h + (size_t)d1 * 64 + quad * 8;
    const float* re1 = ea + (size_t)ec1 * 32 + quad * 8;
    const float* rs2 = h + (size_t)s2 * 64 + quad * 8;
    const float* rd2 = h + (size_t)d2 * 64 + quad * 8;
    const float* re2 = ea + (size_t)ec2 * 32 + quad * 8;
    s16x8 fa1[5], fa2[5];
    fa1[0] = ld_cvt8(rs1); fa1[1] = ld_cvt8(rs1 + 32);
    fa1[2] = ld_cvt8(rd1); fa1[3] = ld_cvt8(rd1 + 32);
    fa1[4] = ld_cvt8(re1);
    fa2[0] = ld_cvt8(rs2); fa2[1] = ld_cvt8(rs2 + 32);
    fa2[2] = ld_cvt8(rd2); fa2[3] = ld_cvt8(rd2 + 32);
    fa2[4] = ld_cvt8(re2);

    // ---- L1: 160 -> 128; each W1 fragment feeds both groups
    f32x4 aA[8], aB[8];
    #pragma unroll
    for (int nt = 0; nt < 8; nt++) { aA[nt] = (f32x4){0.f,0.f,0.f,0.f}; aB[nt] = (f32x4){0.f,0.f,0.f,0.f}; }
    #pragma unroll
    for (int kb = 0; kb < 5; kb++) {
      #pragma unroll
      for (int nt = 0; nt < 8; nt++) {
        s16x8 b = *(const s16x8*)&W1[(nt * 16 + l15) * 168 + kb * 32 + quad * 8];
        aA[nt] = __builtin_amdgcn_mfma_f32_16x16x32_bf16(fa1[kb], b, aA[nt], 0, 0, 0);
        aB[nt] = __builtin_amdgcn_mfma_f32_16x16x32_bf16(fa2[kb], b, aB[nt], 0, 0, 0);
      }
    }
    // act1 = relu(acc + b1); rows 0-15 = group1, 16-31 = group2
    {
      union { float4 v[2]; float f[8]; } b1u;
      b1u.v[0] = *(const float4*)&bf[l15 * 12];
      b1u.v[1] = *(const float4*)&bf[l15 * 12 + 4];
      #pragma unroll
      for (int g = 0; g < 2; g++) {
        #pragma unroll
        for (int nt = 0; nt < 8; nt++) {
          int cb = 2 * nt + (l15 >> 3);
          #pragma unroll
          for (int r = 0; r < 4; r++) {
            int row = g * 16 + quad * 4 + r;
            int cbx = cb ^ (row & 7) ^ ((row >> 3) << 2);
            float v = (g ? aB[nt][r] : aA[nt][r]) + b1u.f[nt];
            v = v > 0.f ? v : 0.f;
            act[row * 128 + (cbx << 3) + sw] = f2bf(v);
          }
        }
      }
    }

    // ---- L2: 128 -> 128; A-frags for both groups, B shared
    f32x4 cA[8], cB[8];
    #pragma unroll
    for (int nt = 0; nt < 8; nt++) { cA[nt] = (f32x4){0.f,0.f,0.f,0.f}; cB[nt] = (f32x4){0.f,0.f,0.f,0.f}; }
    const int hi1 = (l15 >> 3) << 2;        // (row>>3)<<2 for row=l15
    const int hi2 = (2 + (l15 >> 3)) << 2;  // for row=16+l15
    #pragma unroll
    for (int kb = 0; kb < 4; kb++) {
      int base = (kb << 2) + quad;
      s16x8 a1 = *(const s16x8*)&act[l15 * 128 + (((base ^ sw ^ hi1)) << 3)];
      s16x8 a2 = *(const s16x8*)&act[(16 + l15) * 128 + (((base ^ sw ^ hi2)) << 3)];
      int wblk = (base ^ sw) << 3;
      #pragma unroll
      for (int nt = 0; nt < 8; nt++) {
        s16x8 b = *(const s16x8*)&W2[(nt * 16 + l15) * 128 + wblk];
        cA[nt] = __builtin_amdgcn_mfma_f32_16x16x32_bf16(a1, b, cA[nt], 0, 0, 0);
        cB[nt] = __builtin_amdgcn_mfma_f32_16x16x32_bf16(a2, b, cB[nt], 0, 0, 0);
      }
    }
    {
      union { float4 v[2]; float f[8]; } b2u;
      b2u.v[0] = *(const float4*)&bf[192 + l15 * 12];
      b2u.v[1] = *(const float4*)&bf[192 + l15 * 12 + 4];
      #pragma unroll
      for (int g = 0; g < 2; g++) {
        #pragma unroll
        for (int nt = 0; nt < 8; nt++) {
          int cb = 2 * nt + (l15 >> 3);
          #pragma unroll
          for (int r = 0; r < 4; r++) {
            int row = g * 16 + quad * 4 + r;
            int cbx = cb ^ (row & 7) ^ ((row >> 3) << 2);
            float v = (g ? cB[nt][r] : cA[nt][r]) + b2u.f[nt];
            v = v > 0.f ? v : 0.f;
            act[row * 128 + (cbx << 3) + sw] = f2bf(v);
          }
        }
      }
    }

    // ---- L3: 128 -> 64
    f32x4 dA[4], dB[4];
    #pragma unroll
    for (int nt = 0; nt < 4; nt++) { dA[nt] = (f32x4){0.f,0.f,0.f,0.f}; dB[nt] = (f32x4){0.f,0.f,0.f,0.f}; }
    #pragma unroll
    for (int kb = 0; kb < 4; kb++) {
      int base = (kb << 2) + quad;
      s16x8 a1 = *(const s16x8*)&act[l15 * 128 + (((base ^ sw ^ hi1)) << 3)];
      s16x8 a2 = *(const s16x8*)&act[(16 + l15) * 128 + (((base ^ sw ^ hi2)) << 3)];
      int wblk = (base ^ sw) << 3;
      #pragma unroll
      for (int nt = 0; nt < 4; nt++) {
        s16x8 b = *(const s16x8*)&W3[(nt * 16 + l15) * 128 + wblk];
        dA[nt] = __builtin_amdgcn_mfma_f32_16x16x32_bf16(a1, b, dA[nt], 0, 0, 0);
        dB[nt] = __builtin_amdgcn_mfma_f32_16x16x32_bf16(a2, b, dB[nt], 0, 0, 0);
      }
    }

    // ---- LayerNorm in registers + store, per group
    {
      union { float4 v; float f[4]; } b3u, gu, btu;
      b3u.v = *(const float4*)&bf[384 + l15 * 4];
      gu.v  = *(const float4*)&bf[448 + l15 * 4];
      btu.v = *(const float4*)&bf[512 + l15 * 4];
      #pragma unroll
      for (int g = 0; g < 2; g++) {
        #pragma unroll
        for (int r = 0; r < 4; r++) {
          float v0 = (g ? dB[0][r] : dA[0][r]) + b3u.f[0];
          float v1 = (g ? dB[1][r] : dA[1][r]) + b3u.f[1];
          float v2 = (g ? dB[2][r] : dA[2][r]) + b3u.f[2];
          float v3 = (g ? dB[3][r] : dA[3][r]) + b3u.f[3];
          float p = v0 + v1 + v2 + v3;
          float q = v0 * v0 + v1 * v1 + v2 * v2 + v3 * v3;
          #pragma unroll
          for (int m = 1; m <= 8; m <<= 1) {
            p += __shfl_xor(p, m);
            q += __shfl_xor(q, m);
          }
          float mu = p * (1.f / 64.f);
          float var = q * (1.f / 64.f) - mu * mu;
          float rstd = rsqrtf(var + 1e-5f);
          int row = e0 + g * 16 + quad * 4 + r;
          if (row < E) {
            float* mp = msg_out + (size_t)row * 64 + l15;
            mp[0]  = (v0 - mu) * rstd * gu.f[0] + btu.f[0];
            mp[16] = (v1 - mu) * rstd * gu.f[1] + btu.f[1];
            mp[32] = (v2 - mu) * rstd * gu.f[2] + btu.f[2];
            mp[48] = (v3 - mu) * rstd * gu.f[3] + btu.f[3];
          }
        }
      }
    }
  }
}

// ---------------- aggregation by gather: one node per wave, quad-per-edge float4 ----------------
__global__ __launch_bounds__(256) void agg_kernel(
    const float* __restrict__ msg, const int* __restrict__ rowptr,
    const int* __restrict__ csr, float* __restrict__ agg, int Nn) {
  int node = (blockIdx.x * 256 + threadIdx.x) >> 6;
  int lane = threadIdx.x & 63;
  int eo = lane >> 4, l = lane & 15;
  if (node >= Nn) return;
  int s = rowptr[node], e = rowptr[node + 1];
  float4 a = {0.f, 0.f, 0.f, 0.f};
  for (int j = s + eo; j < e; j += 4) {
    const float4 m = *(const float4*)&msg[(size_t)csr[j] * 64 + l * 4];
    a.x += m.x; a.y += m.y; a.z += m.z; a.w += m.w;
  }
  a.x += __shfl_xor(a.x, 16); a.y += __shfl_xor(a.y, 16);
  a.z += __shfl_xor(a.z, 16); a.w += __shfl_xor(a.w, 16);
  a.x += __shfl_xor(a.x, 32); a.y += __shfl_xor(a.y, 32);
  a.z += __shfl_xor(a.z, 32); a.w += __shfl_xor(a.w, 32);
  if (eo == 0) *(float4*)&agg[(size_t)node * 64 + l * 4] = a;
}

// ---------------- update MLP: 16 waves, 16 nodes/tile/wave (R7-verified) ----------------
__global__ __attribute__((amdgpu_flat_work_group_size(1024, 1024), amdgpu_waves_per_eu(4, 4)))
void upd_kernel(
    const float* __restrict__ h, const float* __restrict__ agg,
    const unsigned short* __restrict__ wts,
    const float* __restrict__ ub1, const float* __restrict__ ub2, const float* __restrict__ ub3,
    const float* __restrict__ ug, const float* __restrict__ ubt,
    float* __restrict__ h_new, int Nn) {
  __shared__ __align__(16) unsigned short lds[74880];   // 149,760 B
  const int tid = threadIdx.x;
  const int w = tid >> 6, lane = tid & 63, quad = lane >> 4, l15 = lane & 15;
  const int sw = l15 & 7;
  const int ntiles = (Nn + 15) >> 4;
  const int stride = gridDim.x * 16;
  int tile = blockIdx.x * 16 + w;

  float4 P[8];
  if (tile < ntiles) {
    int n = (tile << 4) + l15; int nc = n < Nn ? n : 0;
    const float* rh = h + (size_t)nc * 64 + quad * 8;
    const float* rg = agg + (size_t)nc * 64 + quad * 8;
    P[0] = *(const float4*)rh;        P[1] = *(const float4*)(rh + 4);
    P[2] = *(const float4*)(rh + 32); P[3] = *(const float4*)(rh + 36);
    P[4] = *(const float4*)rg;        P[5] = *(const float4*)(rg + 4);
    P[6] = *(const float4*)(rg + 32); P[7] = *(const float4*)(rg + 36);
  }

  for (int i = tid; i < 5120; i += 1024)
    *(s16x8*)&lds[i * 8] = *(const s16x8*)&wts[46080 + i * 8];
  float* bf = (float*)&lds[73728];
  stage_bias(bf, tid, 1024, ub1, ub2, ub3, ug, ubt);
  __syncthreads();

  unsigned short* act = &lds[40960 + w * 2048];
  const unsigned short* W1 = &lds[0];
  const unsigned short* W2 = &lds[16384];
  const unsigned short* W3 = &lds[32768];

  for (; tile < ntiles; tile += stride) {
    const int n0 = tile << 4;
    s16x8 fa[4];
    fa[0] = (s16x8)0; fa[1] = (s16x8)0; fa[2] = (s16x8)0; fa[3] = (s16x8)0;
    {
      union { s16x8 v; __hip_bfloat162 h2[4]; } u0, u1, u2, u3;
      float2 t;
      t.x = P[0].x; t.y = P[0].y; u0.h2[0] = __float22bfloat162_rn(t);
      t.x = P[0].z; t.y = P[0].w; u0.h2[1] = __float22bfloat162_rn(t);
      t.x = P[1].x; t.y = P[1].y; u0.h2[2] = __float22bfloat162_rn(t);
      t.x = P[1].z; t.y = P[1].w; u0.h2[3] = __float22bfloat162_rn(t);
      t.x = P[2].x; t.y = P[2].y; u1.h2[0] = __float22bfloat162_rn(t);
      t.x = P[2].z; t.y = P[2].w; u1.h2[1] = __float22bfloat162_rn(t);
      t.x = P[3].x; t.y = P[3].y; u1.h2[2] = __float22bfloat162_rn(t);
      t.x = P[3].z; t.y = P[3].w; u1.h2[3] = __float22bfloat162_rn(t);
      t.x = P[4].x; t.y = P[4].y; u2.h2[0] = __float22bfloat162_rn(t);
      t.x = P[4].z; t.y = P[4].w; u2.h2[1] = __float22bfloat162_rn(t);
      t.x = P[5].x; t.y = P[5].y; u2.h2[2] = __float22bfloat162_rn(t);
      t.x = P[5].z; t.y = P[5].w; u2.h2[3] = __float22bfloat162_rn(t);
      t.x = P[6].x; t.y = P[6].y; u3.h2[0] = __float22bfloat162_rn(t);
      t.x = P[6].z; t.y = P[6].w; u3.h2[1] = __float22bfloat162_rn(t);
      t.x = P[7].x; t.y = P[7].y; u3.h2[2] = __float22bfloat162_rn(t);
      t.x = P[7].z; t.y = P[7].w; u3.h2[3] = __float22bfloat162_rn(t);
      fa[0] = u0.v; fa[1] = u1.v; fa[2] = u2.v; fa[3] = u3.v;
    }

    {
      int tn = tile + stride;
      if (tn < ntiles) {
        int n = (tn << 4) + l15; int nc = n < Nn ? n : 0;
        const float* rh = h + (size_t)nc * 64 + quad * 8;
        const float* rg = agg + (size_t)nc * 64 + quad * 8;
        P[0] = *(const float4*)rh;        P[1] = *(const float4*)(rh + 4);
        P[2] = *(const float4*)(rh + 32); P[3] = *(const float4*)(rh + 36);
        P[4] = *(const float4*)rg;        P[5] = *(const float4*)(rg + 4);
        P[6] = *(const float4*)(rg + 32); P[7] = *(const float4*)(rg + 36);
      }
    }

    f32x4 acc[8];
    #pragma unroll
    for (int nt = 0; nt < 8; nt++) acc[nt] = (f32x4){0.f, 0.f, 0.f, 0.f};
    #pragma unroll
    for (int kb = 0; kb < 4; kb++) {
      int blk8 = (((kb << 2) + quad) ^ sw) << 3;
      #pragma unroll
      for (int nt = 0; nt < 8; nt++) {
        s16x8 b = *(const s16x8*)&W1[(nt * 16 + l15) * 128 + blk8];
        acc[nt] = __builtin_amdgcn_mfma_f32_16x16x32_bf16(fa[kb], b, acc[nt], 0, 0, 0);
      }
    }
    {
      union { float4 v[2]; float f[8]; } b1u;
      b1u.v[0] = *(const float4*)&bf[l15 * 12];
      b1u.v[1] = *(const float4*)&bf[l15 * 12 + 4];
      #pragma unroll
      for (int nt = 0; nt < 8; nt++) {
        int cb = 2 * nt + (l15 >> 3);
        #pragma unroll
        for (int r = 0; r < 4; r++) {
          int row = quad * 4 + r;
          float v = acc[nt][r] + b1u.f[nt];
          v = v > 0.f ? v : 0.f;
          act[row * 128 + ((cb ^ (row & 7)) << 3) + sw] = f2bf(v);
        }
      }
    }

    f32x4 acc2[8];
    #pragma unroll
    for (int nt = 0; nt < 8; nt++) acc2[nt] = (f32x4){0.f, 0.f, 0.f, 0.f};
    #pragma unroll
    for (int kb = 0; kb < 4; kb++) {
      int blk8 = (((kb << 2) + quad) ^ sw) << 3;
      s16x8 a = *(const s16x8*)&act[l15 * 128 + blk8];
      #pragma unroll
      for (int nt = 0; nt < 8; nt++) {
        s16x8 b = *(const s16x8*)&W2[(nt * 16 + l15) * 128 + blk8];
        acc2[nt] = __builtin_amdgcn_mfma_f32_16x16x32_bf16(a, b, acc2[nt], 0, 0, 0);
      }
    }
    {
      union { float4 v[2]; float f[8]; } b2u;
      b2u.v[0] = *(const float4*)&bf[192 + l15 * 12];
      b2u.v[1] = *(const float4*)&bf[192 + l15 * 12 + 4];
      #pragma unroll
      for (int nt = 0; nt < 8; nt++) {
        int cb = 2 * nt + (l15 >> 3);
        #pragma unroll
        for (int r = 0; r < 4; r++) {
          int row = quad * 4 + r;
          float v = acc2[nt][r] + b2u.f[nt];
          v = v > 0.f ? v : 0.f;
          act[row * 128 + ((cb ^ (row & 7)) << 3) + sw] = f2bf(v);
        }
      }
    }

    f32x4 acc3[4];
    #pragma unroll
    for (int nt = 0; nt < 4; nt++) acc3[nt] = (f32x4){0.f, 0.f, 0.f, 0.f};
    #pragma unroll
    for (int kb = 0; kb < 4; kb++) {
      int blk8 = (((kb << 2) + quad) ^ sw) << 3;
      s16x8 a = *(const s16x8*)&act[l15 * 128 + blk8];
      #pragma unroll
      for (int nt = 0; nt < 4; nt++) {
        s16x8 b = *(const s16x8*)&W3[(nt * 16 + l15) * 128 + blk8];
        acc3[nt] = __builtin_amdgcn_mfma_f32_16x16x32_bf16(a, b, acc3[nt], 0, 0, 0);
      }
    }

    {
      union { float4 v; float f[4]; } b3u, gu, btu;
      b3u.v = *(const float4*)&bf[384 + l15 * 4];
      gu.v  = *(const float4*)&bf[448 + l15 * 4];
      btu.v = *(const float4*)&bf[512 + l15 * 4];
      #pragma unroll
      for (int r = 0; r < 4; r++) {
        float v0 = acc3[0][r] + b3u.f[0];
        float v1 = acc3[1][r] + b3u.f[1];
        float v2 = acc3[2][r] + b3u.f[2];
        float v3 = acc3[3][r] + b3u.f[3];
        float p = v0 + v1 + v2 + v3;
        float q = v0 * v0 + v1 * v1 + v2 * v2 + v3 * v3;
        #pragma unroll
        for (int m = 1; m <= 8; m <<= 1) {
          p += __shfl_xor(p, m);
          q += __shfl_xor(q, m);
        }
        float mu = p * (1.f / 64.f);
        float var = q * (1.f / 64.f) - mu * mu;
        float rstd = rsqrtf(var + 1e-5f);
        int row = n0 + quad * 4 + r;
        if (row < Nn) {
          const float* hp = h + (size_t)row * 64 + l15;
          float* op = h_new + (size_t)row * 64 + l15;
          op[0]  = (v0 - mu) * rstd * gu.f[0] + btu.f[0] + hp[0];
          op[16] = (v1 - mu) * rstd * gu.f[1] + btu.f[1] + hp[16];
          op[32] = (v2 - mu) * rstd * gu.f[2] + btu.f[2] + hp[32];
          op[48] = (v3 - mu) * rstd * gu.f[3] + btu.f[3] + hp[48];
        }
      }
    }
  }
}

extern "C" void kernel_launch(void* const* d_in, const int* in_sizes, int n_in,
                              void* d_out, int out_size, void* d_ws, size_t ws_size,
                              hipStream_t stream) {
  const float* h   = (const float*)d_in[0];
  const int*   ei  = (const int*)d_in[1];
  const float* ea  = (const float*)d_in[2];
  const float* mW1 = (const float*)d_in[3];
  const float* mb1 = (const float*)d_in[4];
  const float* mW2 = (const float*)d_in[5];
  const float* mb2 = (const float*)d_in[6];
  const float* mW3 = (const float*)d_in[7];
  const float* mb3 = (const float*)d_in[8];
  const float* mg  = (const float*)d_in[9];
  const float* mbt = (const float*)d_in[10];
  const float* uW1 = (const float*)d_in[11];
  const float* ub1 = (const float*)d_in[12];
  const float* uW2 = (const float*)d_in[13];
  const float* ub2 = (const float*)d_in[14];
  const float* uW3 = (const float*)d_in[15];
  const float* ub3 = (const float*)d_in[16];
  const float* ug  = (const float*)d_in[17];
  const float* ubt = (const float*)d_in[18];

  const int N = in_sizes[0] / 64;
  const int E = in_sizes[2] / 32;
  const int* dstI = ei + E;

  char* ws = (char*)d_ws;
  float* agg          = (float*)ws;              ws += (size_t)N * 64 * 4;
  unsigned short* wts = (unsigned short*)ws;     ws += 87040 * 2;
  ws = (char*)(((size_t)ws + 255) & ~(size_t)255);
  int* deg            = (int*)ws;                ws += (size_t)N * 4;
  int* rowptr         = (int*)ws;                ws += (size_t)(N + 1) * 4;
  ws = (char*)(((size_t)ws + 255) & ~(size_t)255);
  int* cursor         = (int*)ws;                ws += (size_t)N * 4;
  ws = (char*)(((size_t)ws + 255) & ~(size_t)255);
  int* csr            = (int*)ws;                ws += (size_t)E * 4;

  float* h_new = (float*)d_out;
  float* msg   = (float*)d_out + (size_t)N * 64;

  hipMemsetAsync(deg, 0, (size_t)N * sizeof(int), stream);
  wconv<<<dim3((86016 + 255) / 256), dim3(256), 0, stream>>>(mW1, mW2, mW3, uW1, uW2, uW3, wts);
  hist_kernel<<<dim3((E + 255) / 256), dim3(256), 0, stream>>>(dstI, deg, E);
  scan_kernel<<<dim3(1), dim3(1024), 0, stream>>>(deg, rowptr, cursor, N);
  scatter_kernel<<<dim3((E + 255) / 256), dim3(256), 0, stream>>>(dstI, cursor, csr, E);
  msg_kernel<<<dim3(256), dim3(512), 0, stream>>>(
      h, ei, ea, wts, mb1, mb2, mb3, mg, mbt, msg, E);
  agg_kernel<<<dim3((N + 3) / 4), dim3(256), 0, stream>>>(msg, rowptr, csr, agg, N);
  upd_kernel<<<dim3(256), dim3(1024), 0, stream>>>(
      h, agg, wts, ub1, ub2, ub3, ug, ubt, h_new, N);
}

// Round 5
// 356.653 us; speedup vs baseline: 1.6382x; 1.3686x over previous
//
#include <hip/hip_runtime.h>
#include <hip/hip_bf16.h>

// EdgeConv fused GNN. R9: CSR/agg chain deleted — aggregation by fp32 atomicAdd
// done inside msg_kernel while messages are still in registers.
// Pipeline: memset(agg) -> wconv -> msg(+atomic agg) -> upd.   (8 -> 4 dispatches)
// - msg: R8-verified structure (512 thr / 8 waves, 32 edges per wave-tile,
//   dual-group MFMA sharing each weight fragment, VGPR 116 no-spill).
// - dst row index for LN row quad*4+r obtained via __shfl from the lane that
//   gathered it; 4 atomics per lane per r (64B-line friendly: 16 lanes consecutive).
// - upd unchanged (R7/R8-verified).

typedef __attribute__((ext_vector_type(8))) short s16x8;   // MFMA A/B frag (8 bf16)
typedef __attribute__((ext_vector_type(4))) float f32x4;   // MFMA C/D frag

__device__ __forceinline__ unsigned short f2bf(float x) {
  union { float f; unsigned u; } v; v.f = x;
  unsigned r = v.u + 0x7fffu + ((v.u >> 16) & 1u);   // RNE
  return (unsigned short)(r >> 16);
}

__device__ __forceinline__ s16x8 ld_cvt8(const float* p) {
  float4 a = *(const float4*)p;
  float4 b = *(const float4*)(p + 4);
  union { s16x8 v; __hip_bfloat162 h2[4]; } u;
  float2 t;
  t.x = a.x; t.y = a.y; u.h2[0] = __float22bfloat162_rn(t);
  t.x = a.z; t.y = a.w; u.h2[1] = __float22bfloat162_rn(t);
  t.x = b.x; t.y = b.y; u.h2[2] = __float22bfloat162_rn(t);
  t.x = b.z; t.y = b.w; u.h2[3] = __float22bfloat162_rn(t);
  return u.v;
}

// ---------------- weight transpose+convert into final (swizzled) layout ----------------
// ushort offsets in wts:
//  mW1t @0     : 128 rows x stride 168 (k<160, unswizzled; pad never read)
//  mW2t @21504 : 128 x 128, XOR-swizzled
//  mW3t @37888 :  64 x 128, XOR-swizzled
//  uW1t @46080 : 128 x 128, uW2t @62464, uW3t @78848 (64x128); total 87040 ushorts
__global__ __launch_bounds__(256) void wconv(
    const float* __restrict__ mW1, const float* __restrict__ mW2, const float* __restrict__ mW3,
    const float* __restrict__ uW1, const float* __restrict__ uW2, const float* __restrict__ uW3,
    unsigned short* __restrict__ wts) {
  int t = blockIdx.x * 256 + threadIdx.x;
  const float* src; int K, N, off, base;
  if      (t < 20480) { src = mW1; K = 160; N = 128; off = 0;     base = 0;     }
  else if (t < 36864) { src = mW2; K = 128; N = 128; off = 20480; base = 21504; }
  else if (t < 45056) { src = mW3; K = 128; N = 64;  off = 36864; base = 37888; }
  else if (t < 61440) { src = uW1; K = 128; N = 128; off = 45056; base = 46080; }
  else if (t < 77824) { src = uW2; K = 128; N = 128; off = 61440; base = 62464; }
  else if (t < 86016) { src = uW3; K = 128; N = 64;  off = 77824; base = 78848; }
  else return;
  int local = t - off;
  int n = local / K, k = local - n * K;
  int idx;
  if (K == 160) idx = n * 168 + k;                                        // mW1t: padded, plain
  else          idx = base + n * 128 + ((((k >> 3) ^ (n & 7)) << 3) | (k & 7));
  wts[idx] = f2bf(src[k * N + n]);
}

// bias LDS layout (floats, from bias base):
//  b1 @0   : [l15*12 + nt] nt<8  (stride 12 for b128 alignment + bank spread)
//  b2 @192 : same
//  b3 @384, g @448, bt @512 : [l15*4 + nt] nt<4
__device__ __forceinline__ void stage_bias(float* bf, int tid, int nthr,
    const float* b1, const float* b2, const float* b3,
    const float* g, const float* bt) {
  for (int i = tid; i < 576; i += nthr) {
    float v = 0.f;
    if (i < 192)      { int c = i;       int l = c / 12, nt = c % 12; if (nt < 8) v = b1[nt * 16 + l]; }
    else if (i < 384) { int c = i - 192; int l = c / 12, nt = c % 12; if (nt < 8) v = b2[nt * 16 + l]; }
    else if (i < 448) { int c = i - 384; int l = c / 4,  nt = c % 4;  v = b3[nt * 16 + l]; }
    else if (i < 512) { int c = i - 448; int l = c / 4,  nt = c % 4;  v = g[nt * 16 + l]; }
    else              { int c = i - 512; int l = c / 4,  nt = c % 4;  v = bt[nt * 16 + l]; }
    bf[i] = v;
  }
}

// ---------------- message MLP: 8 waves, 32 edges/tile/wave, dual-group + atomic agg ----------------
__global__ __attribute__((amdgpu_flat_work_group_size(512, 512), amdgpu_waves_per_eu(4, 4)))
void msg_kernel(
    const float* __restrict__ h, const int* __restrict__ ei, const float* __restrict__ ea,
    const unsigned short* __restrict__ wts,
    const float* __restrict__ mb1, const float* __restrict__ mb2, const float* __restrict__ mb3,
    const float* __restrict__ mg, const float* __restrict__ mbt,
    float* __restrict__ msg_out, float* __restrict__ agg, int E) {
  __shared__ __align__(16) unsigned short lds[80000];   // 160,000 B
  const int tid = threadIdx.x;
  const int w = tid >> 6, lane = tid & 63, quad = lane >> 4, l15 = lane & 15;
  const int sw = l15 & 7;
  const int* srcI = ei;
  const int* dstI = ei + E;
  const int ntiles = (E + 31) >> 5;
  const int stride = gridDim.x * 8;
  int tile = blockIdx.x * 8 + w;

  // stage all msg weights (46080 ushorts) + biases once
  for (int i = tid; i < 5760; i += 512)
    *(s16x8*)&lds[i * 8] = *(const s16x8*)&wts[i * 8];
  float* bf = (float*)&lds[78848];
  stage_bias(bf, tid, 512, mb1, mb2, mb3, mg, mbt);
  __syncthreads();

  unsigned short* act = &lds[46080 + w * 4096];   // per-wave 8KB: 32 rows x 128, swizzled
  const unsigned short* W1 = &lds[0];
  const unsigned short* W2 = &lds[21504];
  const unsigned short* W3 = &lds[37888];

  for (; tile < ntiles; tile += stride) {
    const int e0 = tile << 5;
    // ---- gather both 16-edge groups' A-fragments
    int ep1 = e0 + l15, ep2 = e0 + 16 + l15;
    int ec1 = ep1 < E ? ep1 : E - 1;
    int ec2 = ep2 < E ? ep2 : E - 1;
    int s1 = srcI[ec1], d1 = dstI[ec1];
    int s2 = srcI[ec2], d2 = dstI[ec2];
    const float* rs1 = h + (size_t)s1 * 64 + quad * 8;
    const float* rd1 = h + (size_t)d1 * 64 + quad * 8;
    const float* re1 = ea + (size_t)ec1 * 32 + quad * 8;
    const float* rs2 = h + (size_t)s2 * 64 + quad * 8;
    const float* rd2 = h + (size_t)d2 * 64 + quad * 8;
    const float* re2 = ea + (size_t)ec2 * 32 + quad * 8;
    s16x8 fa1[5], fa2[5];
    fa1[0] = ld_cvt8(rs1); fa1[1] = ld_cvt8(rs1 + 32);
    fa1[2] = ld_cvt8(rd1); fa1[3] = ld_cvt8(rd1 + 32);
    fa1[4] = ld_cvt8(re1);
    fa2[0] = ld_cvt8(rs2); fa2[1] = ld_cvt8(rs2 + 32);
    fa2[2] = ld_cvt8(rd2); fa2[3] = ld_cvt8(rd2 + 32);
    fa2[4] = ld_cvt8(re2);

    // ---- L1: 160 -> 128; each W1 fragment feeds both groups
    f32x4 aA[8], aB[8];
    #pragma unroll
    for (int nt = 0; nt < 8; nt++) { aA[nt] = (f32x4){0.f,0.f,0.f,0.f}; aB[nt] = (f32x4){0.f,0.f,0.f,0.f}; }
    #pragma unroll
    for (int kb = 0; kb < 5; kb++) {
      #pragma unroll
      for (int nt = 0; nt < 8; nt++) {
        s16x8 b = *(const s16x8*)&W1[(nt * 16 + l15) * 168 + kb * 32 + quad * 8];
        aA[nt] = __builtin_amdgcn_mfma_f32_16x16x32_bf16(fa1[kb], b, aA[nt], 0, 0, 0);
        aB[nt] = __builtin_amdgcn_mfma_f32_16x16x32_bf16(fa2[kb], b, aB[nt], 0, 0, 0);
      }
    }
    // act1 = relu(acc + b1); rows 0-15 = group1, 16-31 = group2
    {
      union { float4 v[2]; float f[8]; } b1u;
      b1u.v[0] = *(const float4*)&bf[l15 * 12];
      b1u.v[1] = *(const float4*)&bf[l15 * 12 + 4];
      #pragma unroll
      for (int g = 0; g < 2; g++) {
        #pragma unroll
        for (int nt = 0; nt < 8; nt++) {
          int cb = 2 * nt + (l15 >> 3);
          #pragma unroll
          for (int r = 0; r < 4; r++) {
            int row = g * 16 + quad * 4 + r;
            int cbx = cb ^ (row & 7) ^ ((row >> 3) << 2);
            float v = (g ? aB[nt][r] : aA[nt][r]) + b1u.f[nt];
            v = v > 0.f ? v : 0.f;
            act[row * 128 + (cbx << 3) + sw] = f2bf(v);
          }
        }
      }
    }

    // ---- L2: 128 -> 128; A-frags for both groups, B shared
    f32x4 cA[8], cB[8];
    #pragma unroll
    for (int nt = 0; nt < 8; nt++) { cA[nt] = (f32x4){0.f,0.f,0.f,0.f}; cB[nt] = (f32x4){0.f,0.f,0.f,0.f}; }
    const int hi1 = (l15 >> 3) << 2;        // (row>>3)<<2 for row=l15
    const int hi2 = (2 + (l15 >> 3)) << 2;  // for row=16+l15
    #pragma unroll
    for (int kb = 0; kb < 4; kb++) {
      int base = (kb << 2) + quad;
      s16x8 a1 = *(const s16x8*)&act[l15 * 128 + (((base ^ sw ^ hi1)) << 3)];
      s16x8 a2 = *(const s16x8*)&act[(16 + l15) * 128 + (((base ^ sw ^ hi2)) << 3)];
      int wblk = (base ^ sw) << 3;
      #pragma unroll
      for (int nt = 0; nt < 8; nt++) {
        s16x8 b = *(const s16x8*)&W2[(nt * 16 + l15) * 128 + wblk];
        cA[nt] = __builtin_amdgcn_mfma_f32_16x16x32_bf16(a1, b, cA[nt], 0, 0, 0);
        cB[nt] = __builtin_amdgcn_mfma_f32_16x16x32_bf16(a2, b, cB[nt], 0, 0, 0);
      }
    }
    {
      union { float4 v[2]; float f[8]; } b2u;
      b2u.v[0] = *(const float4*)&bf[192 + l15 * 12];
      b2u.v[1] = *(const float4*)&bf[192 + l15 * 12 + 4];
      #pragma unroll
      for (int g = 0; g < 2; g++) {
        #pragma unroll
        for (int nt = 0; nt < 8; nt++) {
          int cb = 2 * nt + (l15 >> 3);
          #pragma unroll
          for (int r = 0; r < 4; r++) {
            int row = g * 16 + quad * 4 + r;
            int cbx = cb ^ (row & 7) ^ ((row >> 3) << 2);
            float v = (g ? cB[nt][r] : cA[nt][r]) + b2u.f[nt];
            v = v > 0.f ? v : 0.f;
            act[row * 128 + (cbx << 3) + sw] = f2bf(v);
          }
        }
      }
    }

    // ---- L3: 128 -> 64
    f32x4 dA[4], dB[4];
    #pragma unroll
    for (int nt = 0; nt < 4; nt++) { dA[nt] = (f32x4){0.f,0.f,0.f,0.f}; dB[nt] = (f32x4){0.f,0.f,0.f,0.f}; }
    #pragma unroll
    for (int kb = 0; kb < 4; kb++) {
      int base = (kb << 2) + quad;
      s16x8 a1 = *(const s16x8*)&act[l15 * 128 + (((base ^ sw ^ hi1)) << 3)];
      s16x8 a2 = *(const s16x8*)&act[(16 + l15) * 128 + (((base ^ sw ^ hi2)) << 3)];
      int wblk = (base ^ sw) << 3;
      #pragma unroll
      for (int nt = 0; nt < 4; nt++) {
        s16x8 b = *(const s16x8*)&W3[(nt * 16 + l15) * 128 + wblk];
        dA[nt] = __builtin_amdgcn_mfma_f32_16x16x32_bf16(a1, b, dA[nt], 0, 0, 0);
        dB[nt] = __builtin_amdgcn_mfma_f32_16x16x32_bf16(a2, b, dB[nt], 0, 0, 0);
      }
    }

    // ---- LayerNorm in registers + store msg + atomic aggregate into agg[dst]
    {
      union { float4 v; float f[4]; } b3u, gu, btu;
      b3u.v = *(const float4*)&bf[384 + l15 * 4];
      gu.v  = *(const float4*)&bf[448 + l15 * 4];
      btu.v = *(const float4*)&bf[512 + l15 * 4];
      #pragma unroll
      for (int g = 0; g < 2; g++) {
        #pragma unroll
        for (int r = 0; r < 4; r++) {
          float v0 = (g ? dB[0][r] : dA[0][r]) + b3u.f[0];
          float v1 = (g ? dB[1][r] : dA[1][r]) + b3u.f[1];
          float v2 = (g ? dB[2][r] : dA[2][r]) + b3u.f[2];
          float v3 = (g ? dB[3][r] : dA[3][r]) + b3u.f[3];
          float p = v0 + v1 + v2 + v3;
          float q = v0 * v0 + v1 * v1 + v2 * v2 + v3 * v3;
          #pragma unroll
          for (int m = 1; m <= 8; m <<= 1) {
            p += __shfl_xor(p, m);
            q += __shfl_xor(q, m);
          }
          float mu = p * (1.f / 64.f);
          float var = q * (1.f / 64.f) - mu * mu;
          float rstd = rsqrtf(var + 1e-5f);
          int row = e0 + g * 16 + quad * 4 + r;
          if (row < E) {
            float o0 = (v0 - mu) * rstd * gu.f[0] + btu.f[0];
            float o1 = (v1 - mu) * rstd * gu.f[1] + btu.f[1];
            float o2 = (v2 - mu) * rstd * gu.f[2] + btu.f[2];
            float o3 = (v3 - mu) * rstd * gu.f[3] + btu.f[3];
            float* mp = msg_out + (size_t)row * 64 + l15;
            mp[0]  = o0;
            mp[16] = o1;
            mp[32] = o2;
            mp[48] = o3;
            // dst of this row's edge lives in lane (quad*4+r) of the same group
            int dd = __shfl(g ? d2 : d1, quad * 4 + r);
            float* ap = agg + (size_t)dd * 64 + l15;
            atomicAdd(ap,      o0);
            atomicAdd(ap + 16, o1);
            atomicAdd(ap + 32, o2);
            atomicAdd(ap + 48, o3);
          }
        }
      }
    }
  }
}

// ---------------- update MLP: 16 waves, 16 nodes/tile/wave (R7/R8-verified) ----------------
__global__ __attribute__((amdgpu_flat_work_group_size(1024, 1024), amdgpu_waves_per_eu(4, 4)))
void upd_kernel(
    const float* __restrict__ h, const float* __restrict__ agg,
    const unsigned short* __restrict__ wts,
    const float* __restrict__ ub1, const float* __restrict__ ub2, const float* __restrict__ ub3,
    const float* __restrict__ ug, const float* __restrict__ ubt,
    float* __restrict__ h_new, int Nn) {
  __shared__ __align__(16) unsigned short lds[74880];   // 149,760 B
  const int tid = threadIdx.x;
  const int w = tid >> 6, lane = tid & 63, quad = lane >> 4, l15 = lane & 15;
  const int sw = l15 & 7;
  const int ntiles = (Nn + 15) >> 4;
  const int stride = gridDim.x * 16;
  int tile = blockIdx.x * 16 + w;

  float4 P[8];
  if (tile < ntiles) {
    int n = (tile << 4) + l15; int nc = n < Nn ? n : 0;
    const float* rh = h + (size_t)nc * 64 + quad * 8;
    const float* rg = agg + (size_t)nc * 64 + quad * 8;
    P[0] = *(const float4*)rh;        P[1] = *(const float4*)(rh + 4);
    P[2] = *(const float4*)(rh + 32); P[3] = *(const float4*)(rh + 36);
    P[4] = *(const float4*)rg;        P[5] = *(const float4*)(rg + 4);
    P[6] = *(const float4*)(rg + 32); P[7] = *(const float4*)(rg + 36);
  }

  for (int i = tid; i < 5120; i += 1024)
    *(s16x8*)&lds[i * 8] = *(const s16x8*)&wts[46080 + i * 8];
  float* bf = (float*)&lds[73728];
  stage_bias(bf, tid, 1024, ub1, ub2, ub3, ug, ubt);
  __syncthreads();

  unsigned short* act = &lds[40960 + w * 2048];
  const unsigned short* W1 = &lds[0];
  const unsigned short* W2 = &lds[16384];
  const unsigned short* W3 = &lds[32768];

  for (; tile < ntiles; tile += stride) {
    const int n0 = tile << 4;
    s16x8 fa[4];
    {
      union { s16x8 v; __hip_bfloat162 h2[4]; } u0, u1, u2, u3;
      float2 t;
      t.x = P[0].x; t.y = P[0].y; u0.h2[0] = __float22bfloat162_rn(t);
      t.x = P[0].z; t.y = P[0].w; u0.h2[1] = __float22bfloat162_rn(t);
      t.x = P[1].x; t.y = P[1].y; u0.h2[2] = __float22bfloat162_rn(t);
      t.x = P[1].z; t.y = P[1].w; u0.h2[3] = __float22bfloat162_rn(t);
      t.x = P[2].x; t.y = P[2].y; u1.h2[0] = __float22bfloat162_rn(t);
      t.x = P[2].z; t.y = P[2].w; u1.h2[1] = __float22bfloat162_rn(t);
      t.x = P[3].x; t.y = P[3].y; u1.h2[2] = __float22bfloat162_rn(t);
      t.x = P[3].z; t.y = P[3].w; u1.h2[3] = __float22bfloat162_rn(t);
      t.x = P[4].x; t.y = P[4].y; u2.h2[0] = __float22bfloat162_rn(t);
      t.x = P[4].z; t.y = P[4].w; u2.h2[1] = __float22bfloat162_rn(t);
      t.x = P[5].x; t.y = P[5].y; u2.h2[2] = __float22bfloat162_rn(t);
      t.x = P[5].z; t.y = P[5].w; u2.h2[3] = __float22bfloat162_rn(t);
      t.x = P[6].x; t.y = P[6].y; u3.h2[0] = __float22bfloat162_rn(t);
      t.x = P[6].z; t.y = P[6].w; u3.h2[1] = __float22bfloat162_rn(t);
      t.x = P[7].x; t.y = P[7].y; u3.h2[2] = __float22bfloat162_rn(t);
      t.x = P[7].z; t.y = P[7].w; u3.h2[3] = __float22bfloat162_rn(t);
      fa[0] = u0.v; fa[1] = u1.v; fa[2] = u2.v; fa[3] = u3.v;
    }

    {
      int tn = tile + stride;
      if (tn < ntiles) {
        int n = (tn << 4) + l15; int nc = n < Nn ? n : 0;
        const float* rh = h + (size_t)nc * 64 + quad * 8;
        const float* rg = agg + (size_t)nc * 64 + quad * 8;
        P[0] = *(const float4*)rh;        P[1] = *(const float4*)(rh + 4);
        P[2] = *(const float4*)(rh + 32); P[3] = *(const float4*)(rh + 36);
        P[4] = *(const float4*)rg;        P[5] = *(const float4*)(rg + 4);
        P[6] = *(const float4*)(rg + 32); P[7] = *(const float4*)(rg + 36);
      }
    }

    f32x4 acc[8];
    #pragma unroll
    for (int nt = 0; nt < 8; nt++) acc[nt] = (f32x4){0.f, 0.f, 0.f, 0.f};
    #pragma unroll
    for (int kb = 0; kb < 4; kb++) {
      int blk8 = (((kb << 2) + quad) ^ sw) << 3;
      #pragma unroll
      for (int nt = 0; nt < 8; nt++) {
        s16x8 b = *(const s16x8*)&W1[(nt * 16 + l15) * 128 + blk8];
        acc[nt] = __builtin_amdgcn_mfma_f32_16x16x32_bf16(fa[kb], b, acc[nt], 0, 0, 0);
      }
    }
    {
      union { float4 v[2]; float f[8]; } b1u;
      b1u.v[0] = *(const float4*)&bf[l15 * 12];
      b1u.v[1] = *(const float4*)&bf[l15 * 12 + 4];
      #pragma unroll
      for (int nt = 0; nt < 8; nt++) {
        int cb = 2 * nt + (l15 >> 3);
        #pragma unroll
        for (int r = 0; r < 4; r++) {
          int row = quad * 4 + r;
          float v = acc[nt][r] + b1u.f[nt];
          v = v > 0.f ? v : 0.f;
          act[row * 128 + ((cb ^ (row & 7)) << 3) + sw] = f2bf(v);
        }
      }
    }

    f32x4 acc2[8];
    #pragma unroll
    for (int nt = 0; nt < 8; nt++) acc2[nt] = (f32x4){0.f, 0.f, 0.f, 0.f};
    #pragma unroll
    for (int kb = 0; kb < 4; kb++) {
      int blk8 = (((kb << 2) + quad) ^ sw) << 3;
      s16x8 a = *(const s16x8*)&act[l15 * 128 + blk8];
      #pragma unroll
      for (int nt = 0; nt < 8; nt++) {
        s16x8 b = *(const s16x8*)&W2[(nt * 16 + l15) * 128 + blk8];
        acc2[nt] = __builtin_amdgcn_mfma_f32_16x16x32_bf16(a, b, acc2[nt], 0, 0, 0);
      }
    }
    {
      union { float4 v[2]; float f[8]; } b2u;
      b2u.v[0] = *(const float4*)&bf[192 + l15 * 12];
      b2u.v[1] = *(const float4*)&bf[192 + l15 * 12 + 4];
      #pragma unroll
      for (int nt = 0; nt < 8; nt++) {
        int cb = 2 * nt + (l15 >> 3);
        #pragma unroll
        for (int r = 0; r < 4; r++) {
          int row = quad * 4 + r;
          float v = acc2[nt][r] + b2u.f[nt];
          v = v > 0.f ? v : 0.f;
          act[row * 128 + ((cb ^ (row & 7)) << 3) + sw] = f2bf(v);
        }
      }
    }

    f32x4 acc3[4];
    #pragma unroll
    for (int nt = 0; nt < 4; nt++) acc3[nt] = (f32x4){0.f, 0.f, 0.f, 0.f};
    #pragma unroll
    for (int kb = 0; kb < 4; kb++) {
      int blk8 = (((kb << 2) + quad) ^ sw) << 3;
      s16x8 a = *(const s16x8*)&act[l15 * 128 + blk8];
      #pragma unroll
      for (int nt = 0; nt < 4; nt++) {
        s16x8 b = *(const s16x8*)&W3[(nt * 16 + l15) * 128 + blk8];
        acc3[nt] = __builtin_amdgcn_mfma_f32_16x16x32_bf16(a, b, acc3[nt], 0, 0, 0);
      }
    }

    {
      union { float4 v; float f[4]; } b3u, gu, btu;
      b3u.v = *(const float4*)&bf[384 + l15 * 4];
      gu.v  = *(const float4*)&bf[448 + l15 * 4];
      btu.v = *(const float4*)&bf[512 + l15 * 4];
      #pragma unroll
      for (int r = 0; r < 4; r++) {
        float v0 = acc3[0][r] + b3u.f[0];
        float v1 = acc3[1][r] + b3u.f[1];
        float v2 = acc3[2][r] + b3u.f[2];
        float v3 = acc3[3][r] + b3u.f[3];
        float p = v0 + v1 + v2 + v3;
        float q = v0 * v0 + v1 * v1 + v2 * v2 + v3 * v3;
        #pragma unroll
        for (int m = 1; m <= 8; m <<= 1) {
          p += __shfl_xor(p, m);
          q += __shfl_xor(q, m);
        }
        float mu = p * (1.f / 64.f);
        float var = q * (1.f / 64.f) - mu * mu;
        float rstd = rsqrtf(var + 1e-5f);
        int row = n0 + quad * 4 + r;
        if (row < Nn) {
          const float* hp = h + (size_t)row * 64 + l15;
          float* op = h_new + (size_t)row * 64 + l15;
          op[0]  = (v0 - mu) * rstd * gu.f[0] + btu.f[0] + hp[0];
          op[16] = (v1 - mu) * rstd * gu.f[1] + btu.f[1] + hp[16];
          op[32] = (v2 - mu) * rstd * gu.f[2] + btu.f[2] + hp[32];
          op[48] = (v3 - mu) * rstd * gu.f[3] + btu.f[3] + hp[48];
        }
      }
    }
  }
}

extern "C" void kernel_launch(void* const* d_in, const int* in_sizes, int n_in,
                              void* d_out, int out_size, void* d_ws, size_t ws_size,
                              hipStream_t stream) {
  const float* h   = (const float*)d_in[0];
  const int*   ei  = (const int*)d_in[1];
  const float* ea  = (const float*)d_in[2];
  const float* mW1 = (const float*)d_in[3];
  const float* mb1 = (const float*)d_in[4];
  const float* mW2 = (const float*)d_in[5];
  const float* mb2 = (const float*)d_in[6];
  const float* mW3 = (const float*)d_in[7];
  const float* mb3 = (const float*)d_in[8];
  const float* mg  = (const float*)d_in[9];
  const float* mbt = (const float*)d_in[10];
  const float* uW1 = (const float*)d_in[11];
  const float* ub1 = (const float*)d_in[12];
  const float* uW2 = (const float*)d_in[13];
  const float* ub2 = (const float*)d_in[14];
  const float* uW3 = (const float*)d_in[15];
  const float* ub3 = (const float*)d_in[16];
  const float* ug  = (const float*)d_in[17];
  const float* ubt = (const float*)d_in[18];

  const int N = in_sizes[0] / 64;
  const int E = in_sizes[2] / 32;

  char* ws = (char*)d_ws;
  float* agg          = (float*)ws;              ws += (size_t)N * 64 * 4;
  unsigned short* wts = (unsigned short*)ws;     ws += 87040 * 2;

  float* h_new = (float*)d_out;
  float* msg   = (float*)d_out + (size_t)N * 64;

  hipMemsetAsync(agg, 0, (size_t)N * 64 * sizeof(float), stream);
  wconv<<<dim3((86016 + 255) / 256), dim3(256), 0, stream>>>(mW1, mW2, mW3, uW1, uW2, uW3, wts);
  msg_kernel<<<dim3(256), dim3(512), 0, stream>>>(
      h, ei, ea, wts, mb1, mb2, mb3, mg, mbt, msg, agg, E);
  upd_kernel<<<dim3(256), dim3(1024), 0, stream>>>(
      h, agg, wts, ub1, ub2, ub3, ug, ubt, h_new, N);
}